// Round 1
// baseline (1279.260 us; speedup 1.0000x reference)
//
#include <hip/hip_runtime.h>
#include <math.h>

#define B_ 2
#define N_ 512
#define D_ 1024
#define H_ 16
#define G_ 4
#define HD_ 64
#define NC_ 1536
#define NK_ 2048

// ---------------------------------------------------------------------------
// Generic tiled fp32 GEMM: C(M x Ncols) = A(M x K) @ W(K x Ncols), row-major.
// 64x64 tile per 256-thread block, 4x4 micro-tile per thread, K staged 16.
// mode 0: qs epilogue (scale 0.125, row-major out)
// mode 1: kpT epilogue  out[((b*4+g)*64+d)*512 + i]
// mode 2: vp epilogue   out[((b*4+g)*512+i)*64 + d]
// mode 3: plain row-major out
// ---------------------------------------------------------------------------
__global__ __launch_bounds__(256) void gemm_mk(const float* __restrict__ A,
                                               const float* __restrict__ W,
                                               float* __restrict__ out,
                                               int K, int Ncols, int mode)
{
    __shared__ float As[64][17];   // [m][k] padded to kill 4-way bank conflict
    __shared__ float Bs[16][64];   // [k][n]
    const int tid = threadIdx.x;
    const int tn = tid & 15, tm = tid >> 4;
    const int m0 = blockIdx.y * 64, n0 = blockIdx.x * 64;
    float c[4][4] = {};
    for (int k0 = 0; k0 < K; k0 += 16) {
        for (int idx = tid; idx < 64 * 16; idx += 256) {
            int m = idx >> 4, kk = idx & 15;
            As[m][kk] = A[(size_t)(m0 + m) * K + k0 + kk];
        }
        for (int idx = tid; idx < 16 * 64; idx += 256) {
            int kk = idx >> 6, n = idx & 63;
            Bs[kk][n] = W[(size_t)(k0 + kk) * Ncols + n0 + n];
        }
        __syncthreads();
        #pragma unroll
        for (int kk = 0; kk < 16; ++kk) {
            float a[4], b[4];
            #pragma unroll
            for (int r = 0; r < 4; r++) a[r] = As[tm * 4 + r][kk];
            #pragma unroll
            for (int cc = 0; cc < 4; cc++) b[cc] = Bs[kk][tn * 4 + cc];
            #pragma unroll
            for (int r = 0; r < 4; r++)
                #pragma unroll
                for (int cc = 0; cc < 4; cc++) c[r][cc] += a[r] * b[cc];
        }
        __syncthreads();
    }
    #pragma unroll
    for (int r = 0; r < 4; r++) {
        #pragma unroll
        for (int cc = 0; cc < 4; cc++) {
            int m = m0 + tm * 4 + r, n = n0 + tn * 4 + cc;
            float v = c[r][cc];
            if (mode == 0) {
                out[(size_t)m * Ncols + n] = v * 0.125f;
            } else if (mode == 3) {
                out[(size_t)m * Ncols + n] = v;
            } else {
                int b = m >> 9, i = m & 511, g = n >> 6, d = n & 63;
                if (mode == 1) out[(((size_t)(b * 4 + g) * 64 + d) * 512) + i] = v;
                else           out[(((size_t)(b * 4 + g) * 512 + i) * 64) + d] = v;
            }
        }
    }
}

// ---------------------------------------------------------------------------
// Scores: S[bh][i][j] = sum_d qs[b, i, h*64+d] * kfull[bh][d][j]   (K = 64)
// kfull: j < 1536 -> cache_k[bh][d][j] ; j >= 1536 -> kpT[bh/4][d][j-1536]
// ---------------------------------------------------------------------------
__global__ __launch_bounds__(256) void scores_kernel(const float* __restrict__ qs,
                                                     const float* __restrict__ cache_k,
                                                     const float* __restrict__ kpT,
                                                     float* __restrict__ S)
{
    __shared__ float As[64][65];   // [i][d]
    __shared__ float Bs[64][64];   // [d][j]
    const int bh = blockIdx.z;
    const int b = bh >> 4, h = bh & 15;
    const int i0 = blockIdx.y * 64, j0 = blockIdx.x * 64;
    const int tid = threadIdx.x, tn = tid & 15, tm = tid >> 4;

    for (int idx = tid; idx < 64 * 64; idx += 256) {
        int i = idx >> 6, d = idx & 63;
        As[i][d] = qs[((size_t)b * 512 + i0 + i) * 1024 + h * 64 + d];
    }
    const bool from_cache = (j0 < NC_);
    for (int idx = tid; idx < 64 * 64; idx += 256) {
        int d = idx >> 6, j = idx & 63;
        Bs[d][j] = from_cache
            ? cache_k[((size_t)bh * 64 + d) * 1536 + j0 + j]
            : kpT[(((size_t)(bh >> 2) * 64) + d) * 512 + (j0 - 1536) + j];
    }
    __syncthreads();
    float c[4][4] = {};
    #pragma unroll
    for (int d = 0; d < 64; ++d) {
        float a[4], bb[4];
        #pragma unroll
        for (int r = 0; r < 4; r++) a[r] = As[tm * 4 + r][d];
        #pragma unroll
        for (int cc = 0; cc < 4; cc++) bb[cc] = Bs[d][tn * 4 + cc];
        #pragma unroll
        for (int r = 0; r < 4; r++)
            #pragma unroll
            for (int cc = 0; cc < 4; cc++) c[r][cc] += a[r] * bb[cc];
    }
    #pragma unroll
    for (int r = 0; r < 4; r++)
        #pragma unroll
        for (int cc = 0; cc < 4; cc++) {
            int i = i0 + tm * 4 + r, j = j0 + tn * 4 + cc;
            S[((size_t)bh * 512 + i) * 2048 + j] = c[r][cc];
        }
}

// ---------------------------------------------------------------------------
// Row softmax with fused relative-position bias.
// bias[bh,i,j] = bt[rel_t(i,j)] + bf[rel_f(i,j)], computed per row in LDS.
// ---------------------------------------------------------------------------
__global__ __launch_bounds__(256) void softmax_kernel(const float* __restrict__ qs,
                                                      const float* __restrict__ emb_t,
                                                      const float* __restrict__ emb_f,
                                                      float* __restrict__ S)
{
    __shared__ float qrow[64];
    __shared__ float bt[255];
    __shared__ float bf[15];
    __shared__ float red[4];
    const int i = blockIdx.x;
    const int bh = blockIdx.y;
    const int b = bh >> 4, h = bh & 15;
    const int t = threadIdx.x;

    if (t < 64) qrow[t] = qs[((size_t)b * 512 + i) * 1024 + h * 64 + t];
    __syncthreads();
    if (t < 255) {
        float acc = 0.f;
        #pragma unroll 8
        for (int d = 0; d < 64; d++) acc += qrow[d] * emb_t[t * 64 + d];
        bt[t] = acc;
    }
    if (t < 15) {
        float acc = 0.f;
        #pragma unroll 8
        for (int d = 0; d < 64; d++) acc += qrow[d] * emb_f[t * 64 + d];
        bf[t] = acc;
    }
    __syncthreads();

    const size_t rowoff = ((size_t)bh * 512 + i) * 2048;
    const int qt = 192 + (i >> 3);
    const int ifr = i & 7;
    float v[8];
    float lmax = -1e30f;
    #pragma unroll
    for (int jj = 0; jj < 8; jj++) {
        int j = jj * 256 + t;
        int kt = j >> 3;
        int rel = qt - kt;
        rel = min(127, max(-127, rel));
        int rf = ifr - (j & 7) + 7;
        float val = S[rowoff + j] + bt[rel + 127] + bf[rf];
        v[jj] = val;
        lmax = fmaxf(lmax, val);
    }
    #pragma unroll
    for (int off = 32; off; off >>= 1) lmax = fmaxf(lmax, __shfl_down(lmax, off));
    if ((t & 63) == 0) red[t >> 6] = lmax;
    __syncthreads();
    const float m = fmaxf(fmaxf(red[0], red[1]), fmaxf(red[2], red[3]));
    float lsum = 0.f;
    #pragma unroll
    for (int jj = 0; jj < 8; jj++) { v[jj] = __expf(v[jj] - m); lsum += v[jj]; }
    #pragma unroll
    for (int off = 32; off; off >>= 1) lsum += __shfl_down(lsum, off);
    __syncthreads();
    if ((t & 63) == 0) red[t >> 6] = lsum;
    __syncthreads();
    const float inv = 1.0f / (red[0] + red[1] + red[2] + red[3]);
    #pragma unroll
    for (int jj = 0; jj < 8; jj++) S[rowoff + jj * 256 + t] = v[jj] * inv;
}

// ---------------------------------------------------------------------------
// PV: AO[b,i,h*64+d] = sum_j attn[bh][i][j] * vfull[bh][j][d]
// vfull: j<1536 -> cache_v[bh][j][d] ; else vp[bh/4][j-1536][d]
// ---------------------------------------------------------------------------
__global__ __launch_bounds__(256) void pv_kernel(const float* __restrict__ S,
                                                 const float* __restrict__ cache_v,
                                                 const float* __restrict__ vp,
                                                 float* __restrict__ AO)
{
    __shared__ float As[64][65];   // [i][k]
    __shared__ float Bs[64][64];   // [k][d]
    const int bh = blockIdx.y;
    const int i0 = blockIdx.x * 64;
    const int b = bh >> 4, h = bh & 15;
    const int tid = threadIdx.x, tn = tid & 15, tm = tid >> 4;
    float c[4][4] = {};
    for (int k0 = 0; k0 < 2048; k0 += 64) {
        for (int idx = tid; idx < 64 * 64; idx += 256) {
            int i = idx >> 6, kk = idx & 63;
            As[i][kk] = S[((size_t)bh * 512 + i0 + i) * 2048 + k0 + kk];
        }
        const bool fc = (k0 < NC_);
        for (int idx = tid; idx < 64 * 64; idx += 256) {
            int kk = idx >> 6, d = idx & 63;
            Bs[kk][d] = fc ? cache_v[((size_t)bh * 1536 + k0 + kk) * 64 + d]
                           : vp[(((size_t)(bh >> 2) * 512) + (k0 - 1536) + kk) * 64 + d];
        }
        __syncthreads();
        #pragma unroll
        for (int kk = 0; kk < 64; kk++) {
            float a[4], bb[4];
            #pragma unroll
            for (int r = 0; r < 4; r++) a[r] = As[tm * 4 + r][kk];
            #pragma unroll
            for (int cc = 0; cc < 4; cc++) bb[cc] = Bs[kk][tn * 4 + cc];
            #pragma unroll
            for (int r = 0; r < 4; r++)
                #pragma unroll
                for (int cc = 0; cc < 4; cc++) c[r][cc] += a[r] * bb[cc];
        }
        __syncthreads();
    }
    #pragma unroll
    for (int r = 0; r < 4; r++)
        #pragma unroll
        for (int cc = 0; cc < 4; cc++) {
            int i = i0 + tm * 4 + r, d = tn * 4 + cc;
            AO[((size_t)b * 512 + i) * 1024 + h * 64 + d] = c[r][cc];
        }
}

// ---------------------------------------------------------------------------
// Cache shifts (float4 vectorized)
// ---------------------------------------------------------------------------
__global__ __launch_bounds__(256) void copy_newk(const float* __restrict__ cache_k,
                                                 const float* __restrict__ kpT,
                                                 float* __restrict__ out)
{
    int idx = blockIdx.x * 256 + threadIdx.x;   // float4 index, total 32*64*384
    if (idx >= 32 * 64 * 384) return;
    int jj = (idx % 384) * 4;
    int rest = idx / 384;                       // bh*64 + d
    float4 v;
    if (jj < 1024) {
        v = *(const float4*)&cache_k[(size_t)rest * 1536 + jj + 512];
    } else {
        int bh = rest >> 6, d = rest & 63;
        v = *(const float4*)&kpT[(((size_t)(bh >> 2) * 64 + d) * 512) + jj - 1024];
    }
    *(float4*)&out[(size_t)rest * 1536 + jj] = v;
}

__global__ __launch_bounds__(256) void copy_newv(const float* __restrict__ cache_v,
                                                 const float* __restrict__ vp,
                                                 float* __restrict__ out)
{
    int idx = blockIdx.x * 256 + threadIdx.x;   // float4 index, total 32*1536*16
    if (idx >= 32 * 1536 * 16) return;
    int d4 = idx & 15;
    int rest = idx >> 4;                        // bh*1536 + jj
    int bh = rest / 1536, jj = rest % 1536;
    float4 v;
    if (jj < 1024) {
        v = *(const float4*)&cache_v[((size_t)bh * 1536 + jj + 512) * 64 + d4 * 4];
    } else {
        v = *(const float4*)&vp[(((size_t)(bh >> 2) * 512) + jj - 1024) * 64 + d4 * 4];
    }
    *(float4*)&out[(size_t)rest * 64 + d4 * 4] = v;
}

// ---------------------------------------------------------------------------
extern "C" void kernel_launch(void* const* d_in, const int* in_sizes, int n_in,
                              void* d_out, int out_size, void* d_ws, size_t ws_size,
                              hipStream_t stream)
{
    const float* q       = (const float*)d_in[0];
    const float* k       = (const float*)d_in[1];
    const float* v       = (const float*)d_in[2];
    const float* cache_k = (const float*)d_in[3];
    const float* cache_v = (const float*)d_in[4];
    const float* Wq      = (const float*)d_in[5];
    const float* Wk      = (const float*)d_in[6];
    const float* Wv      = (const float*)d_in[7];
    const float* Wo      = (const float*)d_in[8];
    const float* emb_t   = (const float*)d_in[9];
    const float* emb_f   = (const float*)d_in[10];

    float* out   = (float*)d_out;                 // (2,512,1024)
    float* out_k = out + 1048576;                 // (32,64,1536)
    float* out_v = out_k + 3145728;               // (32,1536,64)

    float* ws  = (float*)d_ws;
    float* qs  = ws;                 // 1,048,576
    float* kpT = qs + 1048576;       //   262,144  [bg][d][n]
    float* vp  = kpT + 262144;       //   262,144  [bg][n][d]
    float* AO  = vp + 262144;        // 1,048,576  [b][n][h*64+d]
    float* S   = AO + 1048576;       // 33,554,432 [bh][i][j]

    gemm_mk<<<dim3(16, 16), 256, 0, stream>>>(q, Wq, qs, 1024, 1024, 0);
    gemm_mk<<<dim3(4, 16), 256, 0, stream>>>(k, Wk, kpT, 1024, 256, 1);
    gemm_mk<<<dim3(4, 16), 256, 0, stream>>>(v, Wv, vp, 1024, 256, 2);
    scores_kernel<<<dim3(32, 8, 32), 256, 0, stream>>>(qs, cache_k, kpT, S);
    softmax_kernel<<<dim3(512, 32), 256, 0, stream>>>(qs, emb_t, emb_f, S);
    pv_kernel<<<dim3(8, 32), 256, 0, stream>>>(S, cache_v, vp, AO);
    gemm_mk<<<dim3(16, 16), 256, 0, stream>>>(AO, Wo, out, 1024, 1024, 3);
    copy_newk<<<dim3((32 * 64 * 384 + 255) / 256), 256, 0, stream>>>(cache_k, kpT, out_k);
    copy_newv<<<dim3((32 * 1536 * 16 + 255) / 256), 256, 0, stream>>>(cache_v, vp, out_v);
}

// Round 2
// 332.320 us; speedup vs baseline: 3.8495x; 3.8495x over previous
//
#include <hip/hip_runtime.h>
#include <math.h>

typedef _Float16 half_t;
typedef _Float16 half8  __attribute__((ext_vector_type(8)));
typedef _Float16 half4v __attribute__((ext_vector_type(4)));
typedef float    floatx4 __attribute__((ext_vector_type(4)));

static __device__ __forceinline__ floatx4 mfma16(half8 a, half8 b, floatx4 c) {
    return __builtin_amdgcn_mfma_f32_16x16x32_f16(a, b, c, 0, 0, 0);
}

// ---------------------------------------------------------------------------
// fp32 -> fp16 converts: q, k, v (1M each) + emb_t (255x64 -> 256x64 padded)
// ---------------------------------------------------------------------------
__global__ __launch_bounds__(256) void convert3(const float* __restrict__ q,
                                                const float* __restrict__ k,
                                                const float* __restrict__ v,
                                                const float* __restrict__ emb_t,
                                                half_t* __restrict__ qh,
                                                half_t* __restrict__ kh,
                                                half_t* __restrict__ vh,
                                                half_t* __restrict__ emb_th)
{
    int j = blockIdx.x * 256 + threadIdx.x;     // float4 index, 262144 total
    float4 a = ((const float4*)q)[j];
    float4 b = ((const float4*)k)[j];
    float4 c = ((const float4*)v)[j];
    half4v oa, ob, oc;
    oa[0]=(half_t)a.x; oa[1]=(half_t)a.y; oa[2]=(half_t)a.z; oa[3]=(half_t)a.w;
    ob[0]=(half_t)b.x; ob[1]=(half_t)b.y; ob[2]=(half_t)b.z; ob[3]=(half_t)b.w;
    oc[0]=(half_t)c.x; oc[1]=(half_t)c.y; oc[2]=(half_t)c.z; oc[3]=(half_t)c.w;
    ((half4v*)qh)[j] = oa;
    ((half4v*)kh)[j] = ob;
    ((half4v*)vh)[j] = oc;
    if (j < 4096) {   // emb_th: 256 rows x 64
        int row = j >> 4, col = (j & 15) * 4;
        half4v oe;
        if (row < 255) {
            float4 e = *(const float4*)&emb_t[row * 64 + col];
            oe[0]=(half_t)e.x; oe[1]=(half_t)e.y; oe[2]=(half_t)e.z; oe[3]=(half_t)e.w;
        } else {
            oe[0]=oe[1]=oe[2]=oe[3]=(half_t)0.f;
        }
        ((half4v*)emb_th)[j] = oe;
    }
}

// ---------------------------------------------------------------------------
// Weight transpose-convert: W[k][n] fp32 -> WT[n][k] fp16 (ld 1024)
// z: 0=Wq->WqT, 1=Wk->WkvT[0:256), 2=Wv->WkvT[256:512), 3=Wo->WoT
// ---------------------------------------------------------------------------
__global__ __launch_bounds__(256) void wtrans(const float* __restrict__ Wq,
                                              const float* __restrict__ Wk,
                                              const float* __restrict__ Wv,
                                              const float* __restrict__ Wo,
                                              half_t* __restrict__ WqT,
                                              half_t* __restrict__ WkvT,
                                              half_t* __restrict__ WoT)
{
    const int z = blockIdx.z;
    const float* src; half_t* dst; int Ncols;
    if (z == 0)      { src = Wq; dst = WqT;               Ncols = 1024; }
    else if (z == 1) { src = Wk; dst = WkvT;              Ncols = 256;  }
    else if (z == 2) { src = Wv; dst = WkvT + 256 * 1024; Ncols = 256;  }
    else             { src = Wo; dst = WoT;               Ncols = 1024; }
    const int n0 = blockIdx.x * 64;
    if (n0 >= Ncols) return;
    const int k0 = blockIdx.y * 64;
    __shared__ float t[64][65];
    const int tid = threadIdx.x;
    for (int idx = tid; idx < 4096; idx += 256) {
        int r = idx >> 6, cc = idx & 63;
        t[r][cc] = src[(size_t)(k0 + r) * Ncols + n0 + cc];
    }
    __syncthreads();
    for (int idx = tid; idx < 4096; idx += 256) {
        int r = idx >> 6, cc = idx & 63;
        dst[(size_t)(n0 + r) * 1024 + k0 + cc] = (half_t)t[cc][r];
    }
}

// ---------------------------------------------------------------------------
// cache_k [bh][d][j] fp32 -> Kc [bh][j][d] fp16 ; fused out_k cache-shift copy
// ---------------------------------------------------------------------------
__global__ __launch_bounds__(256) void tc_k(const float* __restrict__ cache_k,
                                            half_t* __restrict__ Kc,
                                            float* __restrict__ out_k)
{
    const int bh = blockIdx.y, j0 = blockIdx.x * 64;
    __shared__ float t[64][65];
    const int tid = threadIdx.x;
    for (int idx = tid; idx < 4096; idx += 256) {
        int d = idx >> 6, jj = idx & 63;
        float v = cache_k[((size_t)bh * 64 + d) * 1536 + j0 + jj];
        t[d][jj] = v;
        int js = j0 + jj;
        if (js >= 512) out_k[((size_t)bh * 64 + d) * 1536 + js - 512] = v;
    }
    __syncthreads();
    for (int idx = tid; idx < 4096; idx += 256) {
        int jj = idx >> 6, d = idx & 63;
        Kc[((size_t)bh * 1536 + j0 + jj) * 64 + d] = (half_t)t[d][jj];
    }
}

// ---------------------------------------------------------------------------
// cache_v [bh][j][d] fp32 -> VcT [bh][d][j] fp16 ; fused out_v cache-shift copy
// ---------------------------------------------------------------------------
__global__ __launch_bounds__(256) void tc_v(const float* __restrict__ cache_v,
                                            half_t* __restrict__ VcT,
                                            float* __restrict__ out_v)
{
    const int bh = blockIdx.y, j0 = blockIdx.x * 64;
    __shared__ float t[64][65];
    const int tid = threadIdx.x;
    for (int idx = tid; idx < 4096; idx += 256) {
        int jj = idx >> 6, d = idx & 63;
        float v = cache_v[((size_t)bh * 1536 + j0 + jj) * 64 + d];
        t[jj][d] = v;
        if (j0 + jj >= 512) out_v[((size_t)bh * 1536 + j0 + jj - 512) * 64 + d] = v;
    }
    __syncthreads();
    for (int idx = tid; idx < 4096; idx += 256) {
        int d = idx >> 6, jj = idx & 63;
        VcT[((size_t)bh * 64 + d) * 1536 + j0 + jj] = (half_t)t[jj][d];
    }
}

// ---------------------------------------------------------------------------
// MFMA GEMM: C = A(MxK) @ Bt(NxK)^T, BM=BN=128, BK=32, 256 thr, 4 waves 64x64.
// mode 0: qs epilogue (fp16, x0.125) | mode 1: fused k/v proj | mode 2: fp32 out
// ---------------------------------------------------------------------------
__global__ __launch_bounds__(256) void gemm_h(const half_t* __restrict__ A,
                                              const half_t* __restrict__ A2,
                                              const half_t* __restrict__ Bt,
                                              int K, int mode,
                                              half_t* __restrict__ hout,
                                              half_t* __restrict__ hout2,
                                              float* __restrict__ fout,
                                              float* __restrict__ out_k,
                                              float* __restrict__ out_v)
{
    __shared__ __align__(16) half_t As[128 * 32];
    __shared__ __align__(16) half_t Bs[128 * 32];
    const int tid = threadIdx.x, w = tid >> 6, l = tid & 63;
    const int quad = l >> 4, lr = l & 15, wm = w >> 1, wn = w & 1;
    const int m0 = blockIdx.y * 128, n0 = blockIdx.x * 128;
    const half_t* Ause = (mode == 1 && n0 >= 256) ? A2 : A;

    floatx4 zero = {0.f, 0.f, 0.f, 0.f};
    floatx4 acc[4][4];
    #pragma unroll
    for (int a = 0; a < 4; a++)
        #pragma unroll
        for (int b = 0; b < 4; b++) acc[a][b] = zero;

    for (int k0 = 0; k0 < K; k0 += 32) {
        #pragma unroll
        for (int cc = 0; cc < 2; cc++) {
            int c = tid + cc * 256, row = c >> 2, g = c & 3;
            *(half8*)&As[row * 32 + g * 8] =
                *(const half8*)&Ause[(size_t)(m0 + row) * K + k0 + g * 8];
            *(half8*)&Bs[row * 32 + g * 8] =
                *(const half8*)&Bt[(size_t)(n0 + row) * K + k0 + g * 8];
        }
        __syncthreads();
        half8 af[4], bfr[4];
        #pragma unroll
        for (int mi = 0; mi < 4; mi++)
            af[mi] = *(const half8*)&As[(wm * 64 + mi * 16 + lr) * 32 + quad * 8];
        #pragma unroll
        for (int ni = 0; ni < 4; ni++)
            bfr[ni] = *(const half8*)&Bs[(wn * 64 + ni * 16 + lr) * 32 + quad * 8];
        #pragma unroll
        for (int mi = 0; mi < 4; mi++)
            #pragma unroll
            for (int ni = 0; ni < 4; ni++)
                acc[mi][ni] = mfma16(af[mi], bfr[ni], acc[mi][ni]);
        __syncthreads();
    }

    #pragma unroll
    for (int mi = 0; mi < 4; mi++)
        #pragma unroll
        for (int ni = 0; ni < 4; ni++)
            #pragma unroll
            for (int r = 0; r < 4; r++) {
                int m = m0 + wm * 64 + mi * 16 + quad * 4 + r;
                int n = n0 + wn * 64 + ni * 16 + lr;
                float v = acc[mi][ni][r];
                if (mode == 0) {
                    hout[(size_t)m * 1024 + n] = (half_t)(v * 0.125f);
                } else if (mode == 2) {
                    fout[(size_t)m * 1024 + n] = v;
                } else {
                    int b = m >> 9, j = m & 511;
                    if (n < 256) {
                        int g = n >> 6, d = n & 63;
                        hout[(size_t)m * 256 + n] = (half_t)v;   // kp_h
                        #pragma unroll
                        for (int t = 0; t < 4; t++)
                            out_k[(((size_t)(b * 16 + g * 4 + t) * 64 + d) * 1536) + 1024 + j] = v;
                    } else {
                        int nn = n - 256, g = nn >> 6, d = nn & 63;
                        hout2[(((size_t)(b * 4 + g) * 64 + d) * 512) + j] = (half_t)v;  // vpT
                        #pragma unroll
                        for (int t = 0; t < 4; t++)
                            out_v[(((size_t)(b * 16 + g * 4 + t) * 1536) + 1024 + j) * 64 + d] = v;
                    }
                }
            }
}

// ---------------------------------------------------------------------------
// bt_all[bh][i][t] = qs[b,i,h*64+:] . emb_t[t][:]   (MFMA, K=64, N=256)
// ---------------------------------------------------------------------------
__global__ __launch_bounds__(256) void bias_h(const half_t* __restrict__ qs_h,
                                              const half_t* __restrict__ emb_th,
                                              half_t* __restrict__ bt_all)
{
    __shared__ __align__(16) half_t Qs[128 * 72];
    __shared__ __align__(16) half_t Ks[128 * 72];
    const int bh = blockIdx.z, b = bh >> 4, h = bh & 15;
    const int i0 = blockIdx.y * 128, t0 = blockIdx.x * 128;
    const int tid = threadIdx.x, w = tid >> 6, l = tid & 63;
    const int quad = l >> 4, lr = l & 15, wm = w >> 1, wn = w & 1;
    #pragma unroll
    for (int it = 0; it < 4; it++) {
        int c = tid + it * 256, row = c >> 3, gg = c & 7;
        *(half8*)&Qs[row * 72 + gg * 8] =
            *(const half8*)&qs_h[((size_t)(b * 512 + i0 + row)) * 1024 + h * 64 + gg * 8];
        *(half8*)&Ks[row * 72 + gg * 8] =
            *(const half8*)&emb_th[(size_t)(t0 + row) * 64 + gg * 8];
    }
    __syncthreads();
    floatx4 zero = {0.f, 0.f, 0.f, 0.f};
    floatx4 acc[4][4];
    #pragma unroll
    for (int a = 0; a < 4; a++)
        #pragma unroll
        for (int bb = 0; bb < 4; bb++) acc[a][bb] = zero;
    #pragma unroll
    for (int ks = 0; ks < 2; ks++) {
        half8 af[4], bfr[4];
        #pragma unroll
        for (int mi = 0; mi < 4; mi++)
            af[mi] = *(const half8*)&Qs[(wm * 64 + mi * 16 + lr) * 72 + ks * 32 + quad * 8];
        #pragma unroll
        for (int ni = 0; ni < 4; ni++)
            bfr[ni] = *(const half8*)&Ks[(wn * 64 + ni * 16 + lr) * 72 + ks * 32 + quad * 8];
        #pragma unroll
        for (int mi = 0; mi < 4; mi++)
            #pragma unroll
            for (int ni = 0; ni < 4; ni++)
                acc[mi][ni] = mfma16(af[mi], bfr[ni], acc[mi][ni]);
    }
    #pragma unroll
    for (int mi = 0; mi < 4; mi++)
        #pragma unroll
        for (int ni = 0; ni < 4; ni++)
            #pragma unroll
            for (int r = 0; r < 4; r++) {
                int i = i0 + wm * 64 + mi * 16 + quad * 4 + r;
                int t = t0 + wn * 64 + ni * 16 + lr;
                bt_all[((size_t)bh * 512 + i) * 256 + t] = (half_t)acc[mi][ni][r];
            }
}

// ---------------------------------------------------------------------------
// Scores: S[bh][i][j] fp16 = qs . K  (K=64), tiles 128x128
// ---------------------------------------------------------------------------
__global__ __launch_bounds__(256) void scores_h(const half_t* __restrict__ qs_h,
                                                const half_t* __restrict__ Kc,
                                                const half_t* __restrict__ kp_h,
                                                half_t* __restrict__ S)
{
    __shared__ __align__(16) half_t Qs[128 * 72];
    __shared__ __align__(16) half_t Ks[128 * 72];
    const int bh = blockIdx.z, b = bh >> 4, h = bh & 15, g = h >> 2;
    const int i0 = blockIdx.y * 128, j0 = blockIdx.x * 128;
    const int tid = threadIdx.x, w = tid >> 6, l = tid & 63;
    const int quad = l >> 4, lr = l & 15, wm = w >> 1, wn = w & 1;
    #pragma unroll
    for (int it = 0; it < 4; it++) {
        int c = tid + it * 256, row = c >> 3, gg = c & 7;
        *(half8*)&Qs[row * 72 + gg * 8] =
            *(const half8*)&qs_h[((size_t)(b * 512 + i0 + row)) * 1024 + h * 64 + gg * 8];
        const half_t* src = (j0 < 1536)
            ? &Kc[((size_t)bh * 1536 + j0 + row) * 64 + gg * 8]
            : &kp_h[((size_t)(b * 512 + j0 - 1536 + row)) * 256 + g * 64 + gg * 8];
        *(half8*)&Ks[row * 72 + gg * 8] = *(const half8*)src;
    }
    __syncthreads();
    floatx4 zero = {0.f, 0.f, 0.f, 0.f};
    floatx4 acc[4][4];
    #pragma unroll
    for (int a = 0; a < 4; a++)
        #pragma unroll
        for (int bb = 0; bb < 4; bb++) acc[a][bb] = zero;
    #pragma unroll
    for (int ks = 0; ks < 2; ks++) {
        half8 af[4], bfr[4];
        #pragma unroll
        for (int mi = 0; mi < 4; mi++)
            af[mi] = *(const half8*)&Qs[(wm * 64 + mi * 16 + lr) * 72 + ks * 32 + quad * 8];
        #pragma unroll
        for (int ni = 0; ni < 4; ni++)
            bfr[ni] = *(const half8*)&Ks[(wn * 64 + ni * 16 + lr) * 72 + ks * 32 + quad * 8];
        #pragma unroll
        for (int mi = 0; mi < 4; mi++)
            #pragma unroll
            for (int ni = 0; ni < 4; ni++)
                acc[mi][ni] = mfma16(af[mi], bfr[ni], acc[mi][ni]);
    }
    #pragma unroll
    for (int mi = 0; mi < 4; mi++)
        #pragma unroll
        for (int ni = 0; ni < 4; ni++)
            #pragma unroll
            for (int r = 0; r < 4; r++) {
                int i = i0 + wm * 64 + mi * 16 + quad * 4 + r;
                int j = j0 + wn * 64 + ni * 16 + lr;
                S[((size_t)bh * 512 + i) * 2048 + j] = (half_t)acc[mi][ni][r];
            }
}

// ---------------------------------------------------------------------------
// Softmax row kernel (in-place on S fp16), bias = bt_all lookup + bf dot
// ---------------------------------------------------------------------------
__global__ __launch_bounds__(256) void softmax_h(const half_t* __restrict__ qs_h,
                                                 const half_t* __restrict__ bt_all,
                                                 const float* __restrict__ emb_f,
                                                 half_t* __restrict__ S)
{
    __shared__ float qrow[64];
    __shared__ float bt[256];
    __shared__ float bf[15];
    __shared__ float red[4];
    const int i = blockIdx.x, bh = blockIdx.y;
    const int b = bh >> 4, h = bh & 15;
    const int t = threadIdx.x;
    if (t < 64) qrow[t] = (float)qs_h[((size_t)(b * 512 + i)) * 1024 + h * 64 + t];
    bt[t] = (float)bt_all[((size_t)bh * 512 + i) * 256 + t];
    __syncthreads();
    if (t < 15) {
        float acc = 0.f;
        #pragma unroll 8
        for (int d = 0; d < 64; d++) acc += qrow[d] * emb_f[t * 64 + d];
        bf[t] = acc;
    }
    __syncthreads();
    const size_t rowoff = ((size_t)bh * 512 + i) * 2048;
    const int qt = 192 + (i >> 3);
    const int ifr = i & 7;
    int rel = qt - t;                       // kt == t for j in [t*8, t*8+8)
    rel = min(127, max(-127, rel));
    const float btv = bt[rel + 127];
    half8 sv = *(const half8*)&S[rowoff + t * 8];
    float v[8];
    float lmax = -1e30f;
    #pragma unroll
    for (int jj = 0; jj < 8; jj++) {
        v[jj] = (float)sv[jj] + btv + bf[ifr - jj + 7];
        lmax = fmaxf(lmax, v[jj]);
    }
    #pragma unroll
    for (int off = 32; off; off >>= 1) lmax = fmaxf(lmax, __shfl_down(lmax, off));
    if ((t & 63) == 0) red[t >> 6] = lmax;
    __syncthreads();
    const float m = fmaxf(fmaxf(red[0], red[1]), fmaxf(red[2], red[3]));
    float lsum = 0.f;
    #pragma unroll
    for (int jj = 0; jj < 8; jj++) { v[jj] = __expf(v[jj] - m); lsum += v[jj]; }
    #pragma unroll
    for (int off = 32; off; off >>= 1) lsum += __shfl_down(lsum, off);
    __syncthreads();
    if ((t & 63) == 0) red[t >> 6] = lsum;
    __syncthreads();
    const float inv = 1.0f / (red[0] + red[1] + red[2] + red[3]);
    half8 ov;
    #pragma unroll
    for (int jj = 0; jj < 8; jj++) ov[jj] = (half_t)(v[jj] * inv);
    *(half8*)&S[rowoff + t * 8] = ov;
}

// ---------------------------------------------------------------------------
// PV: AO[b,i,h*64+d] = P . Vfull, BM=128 i x BN=64 d, BK=64, K=2048
// ---------------------------------------------------------------------------
__global__ __launch_bounds__(256) void pv_h(const half_t* __restrict__ S,
                                            const half_t* __restrict__ VcT,
                                            const half_t* __restrict__ vpT,
                                            half_t* __restrict__ AO)
{
    __shared__ __align__(16) half_t Ps[128 * 72];
    __shared__ __align__(16) half_t Vs[64 * 72];
    const int bh = blockIdx.y, b = bh >> 4, h = bh & 15, g = h >> 2;
    const int i0 = blockIdx.x * 128;
    const int tid = threadIdx.x, w = tid >> 6, l = tid & 63;
    const int quad = l >> 4, lr = l & 15, wm = w >> 1, wn = w & 1;
    floatx4 zero = {0.f, 0.f, 0.f, 0.f};
    floatx4 acc[4][2];
    #pragma unroll
    for (int a = 0; a < 4; a++) { acc[a][0] = zero; acc[a][1] = zero; }

    for (int k0 = 0; k0 < 2048; k0 += 64) {
        #pragma unroll
        for (int it = 0; it < 4; it++) {
            int c = tid + it * 256, row = c >> 3, gg = c & 7;
            *(half8*)&Ps[row * 72 + gg * 8] =
                *(const half8*)&S[((size_t)bh * 512 + i0 + row) * 2048 + k0 + gg * 8];
        }
        #pragma unroll
        for (int it = 0; it < 2; it++) {
            int c = tid + it * 256, d = c >> 3, gg = c & 7;
            const half_t* src = (k0 < 1536)
                ? &VcT[((size_t)bh * 64 + d) * 1536 + k0 + gg * 8]
                : &vpT[((size_t)(b * 4 + g) * 64 + d) * 512 + (k0 - 1536) + gg * 8];
            *(half8*)&Vs[d * 72 + gg * 8] = *(const half8*)src;
        }
        __syncthreads();
        #pragma unroll
        for (int ks = 0; ks < 2; ks++) {
            half8 af[4], bfr[2];
            #pragma unroll
            for (int mi = 0; mi < 4; mi++)
                af[mi] = *(const half8*)&Ps[(wm * 64 + mi * 16 + lr) * 72 + ks * 32 + quad * 8];
            #pragma unroll
            for (int ni = 0; ni < 2; ni++)
                bfr[ni] = *(const half8*)&Vs[(wn * 32 + ni * 16 + lr) * 72 + ks * 32 + quad * 8];
            #pragma unroll
            for (int mi = 0; mi < 4; mi++)
                #pragma unroll
                for (int ni = 0; ni < 2; ni++)
                    acc[mi][ni] = mfma16(af[mi], bfr[ni], acc[mi][ni]);
        }
        __syncthreads();
    }
    #pragma unroll
    for (int mi = 0; mi < 4; mi++)
        #pragma unroll
        for (int ni = 0; ni < 2; ni++)
            #pragma unroll
            for (int r = 0; r < 4; r++) {
                int i = i0 + wm * 64 + mi * 16 + quad * 4 + r;
                int d = wn * 32 + ni * 16 + lr;
                AO[((size_t)(b * 512 + i)) * 1024 + h * 64 + d] = (half_t)acc[mi][ni][r];
            }
}

// ---------------------------------------------------------------------------
extern "C" void kernel_launch(void* const* d_in, const int* in_sizes, int n_in,
                              void* d_out, int out_size, void* d_ws, size_t ws_size,
                              hipStream_t stream)
{
    const float* q       = (const float*)d_in[0];
    const float* k       = (const float*)d_in[1];
    const float* v       = (const float*)d_in[2];
    const float* cache_k = (const float*)d_in[3];
    const float* cache_v = (const float*)d_in[4];
    const float* Wq      = (const float*)d_in[5];
    const float* Wk      = (const float*)d_in[6];
    const float* Wv      = (const float*)d_in[7];
    const float* Wo      = (const float*)d_in[8];
    const float* emb_t   = (const float*)d_in[9];
    const float* emb_f   = (const float*)d_in[10];

    float* out   = (float*)d_out;                 // (2,512,1024)
    float* out_k = out + 1048576;                 // (32,64,1536)
    float* out_v = out_k + 3145728;               // (32,1536,64)

    half_t* ws = (half_t*)d_ws;
    half_t* qh     = ws;                 size_t o = 1048576;
    half_t* kh     = ws + o;             o += 1048576;
    half_t* vh     = ws + o;             o += 1048576;
    half_t* WqT    = ws + o;             o += 1048576;
    half_t* WoT    = ws + o;             o += 1048576;
    half_t* qs_h   = ws + o;             o += 1048576;
    half_t* AO     = ws + o;             o += 1048576;
    half_t* WkvT   = ws + o;             o += 524288;
    half_t* kp_h   = ws + o;             o += 262144;
    half_t* vpT    = ws + o;             o += 262144;
    half_t* emb_th = ws + o;             o += 16384;
    half_t* bt_all = ws + o;             o += 4194304;
    half_t* Kc     = ws + o;             o += 3145728;
    half_t* VcT    = ws + o;             o += 3145728;
    half_t* S      = ws + o;             o += 33554432;

    convert3<<<dim3(1024), 256, 0, stream>>>(q, k, v, emb_t, qh, kh, vh, emb_th);
    wtrans<<<dim3(16, 16, 4), 256, 0, stream>>>(Wq, Wk, Wv, Wo, WqT, WkvT, WoT);
    tc_k<<<dim3(24, 32), 256, 0, stream>>>(cache_k, Kc, out_k);
    tc_v<<<dim3(24, 32), 256, 0, stream>>>(cache_v, VcT, out_v);
    gemm_h<<<dim3(8, 8), 256, 0, stream>>>(qh, nullptr, WqT, 1024, 0,
                                           qs_h, nullptr, nullptr, nullptr, nullptr);
    gemm_h<<<dim3(4, 8), 256, 0, stream>>>(kh, vh, WkvT, 1024, 1,
                                           kp_h, vpT, nullptr, out_k, out_v);
    bias_h<<<dim3(2, 4, 32), 256, 0, stream>>>(qs_h, emb_th, bt_all);
    scores_h<<<dim3(16, 4, 32), 256, 0, stream>>>(qs_h, Kc, kp_h, S);
    softmax_h<<<dim3(512, 32), 256, 0, stream>>>(qs_h, bt_all, emb_f, S);
    pv_h<<<dim3(4, 32), 256, 0, stream>>>(S, VcT, vpT, AO);
    gemm_h<<<dim3(8, 8), 256, 0, stream>>>(AO, nullptr, WoT, 1024, 2,
                                           nullptr, nullptr, out, nullptr, nullptr);
}

// Round 3
// 211.437 us; speedup vs baseline: 6.0503x; 1.5717x over previous
//
#include <hip/hip_runtime.h>
#include <math.h>

typedef _Float16 half_t;
typedef _Float16 half8  __attribute__((ext_vector_type(8)));
typedef float    floatx4 __attribute__((ext_vector_type(4)));

static __device__ __forceinline__ floatx4 mfma16(half8 a, half8 b, floatx4 c) {
    return __builtin_amdgcn_mfma_f32_16x16x32_f16(a, b, c, 0, 0, 0);
}

// ---------------------------------------------------------------------------
// Weight transpose-convert + embc build.
// z 0..3: W[k][n] fp32 -> WT[n][k] fp16 (ld 1024). z=4: embc[320][64]:
// rows 0..254 = emb_t, 256..270 = emb_f, rest 0.
// ---------------------------------------------------------------------------
__global__ __launch_bounds__(256) void wtrans(const float* __restrict__ Wq,
                                              const float* __restrict__ Wk,
                                              const float* __restrict__ Wv,
                                              const float* __restrict__ Wo,
                                              const float* __restrict__ emb_t,
                                              const float* __restrict__ emb_f,
                                              half_t* __restrict__ WqT,
                                              half_t* __restrict__ WkvT,
                                              half_t* __restrict__ WoT,
                                              half_t* __restrict__ embc)
{
    const int z = blockIdx.z;
    const int tid = threadIdx.x;
    if (z == 4) {
        int idx = (blockIdx.y * 16 + blockIdx.x) * 256 + tid;
        if (idx < 320 * 64) {
            int row = idx >> 6, col = idx & 63;
            float val = 0.f;
            if (row < 255) val = emb_t[row * 64 + col];
            else if (row >= 256 && row < 271) val = emb_f[(row - 256) * 64 + col];
            embc[idx] = (half_t)val;
        }
        return;
    }
    const float* src; half_t* dst; int Ncols;
    if (z == 0)      { src = Wq; dst = WqT;               Ncols = 1024; }
    else if (z == 1) { src = Wk; dst = WkvT;              Ncols = 256;  }
    else if (z == 2) { src = Wv; dst = WkvT + 256 * 1024; Ncols = 256;  }
    else             { src = Wo; dst = WoT;               Ncols = 1024; }
    const int n0 = blockIdx.x * 64;
    if (n0 >= Ncols) return;
    const int k0 = blockIdx.y * 64;
    __shared__ float t[64][65];
    for (int idx = tid; idx < 4096; idx += 256) {
        int r = idx >> 6, cc = idx & 63;
        t[r][cc] = src[(size_t)(k0 + r) * Ncols + n0 + cc];
    }
    __syncthreads();
    for (int idx = tid; idx < 4096; idx += 256) {
        int r = idx >> 6, cc = idx & 63;
        dst[(size_t)(n0 + r) * 1024 + k0 + cc] = (half_t)t[cc][r];
    }
}

// ---------------------------------------------------------------------------
// Cache transpose-converts + fused fp32 cache-shift copies.
// z=0: cache_k [bh][d][j] -> Kc [bh][j][d] fp16 ; out_k[j<1024] fp32
// z=1: cache_v [bh][j][d] -> VcT [bh][d][j] fp16 ; out_v[j<1024] fp32
// ---------------------------------------------------------------------------
__global__ __launch_bounds__(256) void tc_kv(const float* __restrict__ cache_k,
                                             const float* __restrict__ cache_v,
                                             half_t* __restrict__ Kc,
                                             half_t* __restrict__ VcT,
                                             float* __restrict__ out_k,
                                             float* __restrict__ out_v)
{
    const int bh = blockIdx.y, j0 = blockIdx.x * 64;
    const int tid = threadIdx.x;
    __shared__ float t[64][65];
    if (blockIdx.z == 0) {
        for (int idx = tid; idx < 4096; idx += 256) {
            int d = idx >> 6, jj = idx & 63;
            float v = cache_k[((size_t)bh * 64 + d) * 1536 + j0 + jj];
            t[d][jj] = v;
            int js = j0 + jj;
            if (js >= 512) out_k[((size_t)bh * 64 + d) * 1536 + js - 512] = v;
        }
        __syncthreads();
        for (int idx = tid; idx < 4096; idx += 256) {
            int jj = idx >> 6, d = idx & 63;
            Kc[((size_t)bh * 1536 + j0 + jj) * 64 + d] = (half_t)t[d][jj];
        }
    } else {
        for (int idx = tid; idx < 4096; idx += 256) {
            int jj = idx >> 6, d = idx & 63;
            float v = cache_v[((size_t)bh * 1536 + j0 + jj) * 64 + d];
            t[jj][d] = v;
            if (j0 + jj >= 512) out_v[((size_t)bh * 1536 + j0 + jj - 512) * 64 + d] = v;
        }
        __syncthreads();
        for (int idx = tid; idx < 4096; idx += 256) {
            int d = idx >> 6, jj = idx & 63;
            VcT[((size_t)bh * 64 + d) * 1536 + j0 + jj] = (half_t)t[jj][d];
        }
    }
}

// ---------------------------------------------------------------------------
// Unified projection GEMM: 64x64 tile, BK=64, double-buffered, 4 waves (2x2,
// each 32x32). phase 0: blocks 0..255 = q-proj (fp16 out, x0.125),
// 256..383 = k/v-proj (LDS-transpose epilogue -> kp_h/vpT fp16 + out_k/out_v
// fp32 new regions). phase 1: out-proj (A = AO fp16, fp32 out).
// ---------------------------------------------------------------------------
__global__ __launch_bounds__(256) void proj(int phase,
                                            const float* __restrict__ qin,
                                            const float* __restrict__ kin,
                                            const float* __restrict__ vin,
                                            const half_t* __restrict__ AO,
                                            const half_t* __restrict__ WqT,
                                            const half_t* __restrict__ WkvT,
                                            const half_t* __restrict__ WoT,
                                            half_t* __restrict__ qs_h,
                                            half_t* __restrict__ kp_h,
                                            half_t* __restrict__ vpT,
                                            float* __restrict__ out,
                                            float* __restrict__ out_k,
                                            float* __restrict__ out_v)
{
    __shared__ __align__(16) half_t As[2][64 * 72];
    __shared__ __align__(16) half_t Bs[2][64 * 72];
    const int id = blockIdx.x;
    int task, m0, n0;
    const float* Af = nullptr; const half_t* Ah = nullptr; const half_t* Bt;
    if (phase == 1)      { task = 2; m0 = (id >> 4) * 64; n0 = (id & 15) * 64; Ah = AO; Bt = WoT; }
    else if (id < 256)   { task = 0; m0 = (id >> 4) * 64; n0 = (id & 15) * 64; Af = qin; Bt = WqT; }
    else { task = 1; int t = id - 256; m0 = (t >> 3) * 64; n0 = (t & 7) * 64;
           Af = (n0 < 256) ? kin : vin; Bt = WkvT; }

    const int tid = threadIdx.x, w = tid >> 6, l = tid & 63;
    const int quad = l >> 4, lr = l & 15, wm = w >> 1, wn = w & 1;
    const int arow = tid >> 2, acol = (tid & 3) * 16;

    // stage tile 0
    {
        if (Af) {
            float4 f0 = *(const float4*)&Af[(size_t)(m0 + arow) * 1024 + acol];
            float4 f1 = *(const float4*)&Af[(size_t)(m0 + arow) * 1024 + acol + 4];
            float4 f2 = *(const float4*)&Af[(size_t)(m0 + arow) * 1024 + acol + 8];
            float4 f3 = *(const float4*)&Af[(size_t)(m0 + arow) * 1024 + acol + 12];
            half8 h0, h1;
            h0[0]=(half_t)f0.x; h0[1]=(half_t)f0.y; h0[2]=(half_t)f0.z; h0[3]=(half_t)f0.w;
            h0[4]=(half_t)f1.x; h0[5]=(half_t)f1.y; h0[6]=(half_t)f1.z; h0[7]=(half_t)f1.w;
            h1[0]=(half_t)f2.x; h1[1]=(half_t)f2.y; h1[2]=(half_t)f2.z; h1[3]=(half_t)f2.w;
            h1[4]=(half_t)f3.x; h1[5]=(half_t)f3.y; h1[6]=(half_t)f3.z; h1[7]=(half_t)f3.w;
            *(half8*)&As[0][arow * 72 + acol] = h0;
            *(half8*)&As[0][arow * 72 + acol + 8] = h1;
        } else {
            *(half8*)&As[0][arow * 72 + acol]     = *(const half8*)&Ah[(size_t)(m0 + arow) * 1024 + acol];
            *(half8*)&As[0][arow * 72 + acol + 8] = *(const half8*)&Ah[(size_t)(m0 + arow) * 1024 + acol + 8];
        }
        *(half8*)&Bs[0][arow * 72 + acol]     = *(const half8*)&Bt[(size_t)(n0 + arow) * 1024 + acol];
        *(half8*)&Bs[0][arow * 72 + acol + 8] = *(const half8*)&Bt[(size_t)(n0 + arow) * 1024 + acol + 8];
    }
    __syncthreads();

    floatx4 zero = {0.f, 0.f, 0.f, 0.f};
    floatx4 acc[2][2];
    acc[0][0] = zero; acc[0][1] = zero; acc[1][0] = zero; acc[1][1] = zero;

    float4 pf0, pf1, pf2, pf3; half8 ph0, ph1, pb0, pb1;
    for (int it = 0; it < 16; ++it) {
        if (it < 15) {
            int kk = (it + 1) * 64;
            if (Af) {
                pf0 = *(const float4*)&Af[(size_t)(m0 + arow) * 1024 + kk + acol];
                pf1 = *(const float4*)&Af[(size_t)(m0 + arow) * 1024 + kk + acol + 4];
                pf2 = *(const float4*)&Af[(size_t)(m0 + arow) * 1024 + kk + acol + 8];
                pf3 = *(const float4*)&Af[(size_t)(m0 + arow) * 1024 + kk + acol + 12];
            } else {
                ph0 = *(const half8*)&Ah[(size_t)(m0 + arow) * 1024 + kk + acol];
                ph1 = *(const half8*)&Ah[(size_t)(m0 + arow) * 1024 + kk + acol + 8];
            }
            pb0 = *(const half8*)&Bt[(size_t)(n0 + arow) * 1024 + kk + acol];
            pb1 = *(const half8*)&Bt[(size_t)(n0 + arow) * 1024 + kk + acol + 8];
        }
        const half_t* Ab = &As[it & 1][0];
        const half_t* Bb = &Bs[it & 1][0];
        #pragma unroll
        for (int ks = 0; ks < 2; ++ks) {
            half8 a0 = *(const half8*)&Ab[(wm * 32 + lr) * 72 + ks * 32 + quad * 8];
            half8 a1 = *(const half8*)&Ab[(wm * 32 + 16 + lr) * 72 + ks * 32 + quad * 8];
            half8 b0 = *(const half8*)&Bb[(wn * 32 + lr) * 72 + ks * 32 + quad * 8];
            half8 b1 = *(const half8*)&Bb[(wn * 32 + 16 + lr) * 72 + ks * 32 + quad * 8];
            acc[0][0] = mfma16(a0, b0, acc[0][0]);
            acc[0][1] = mfma16(a0, b1, acc[0][1]);
            acc[1][0] = mfma16(a1, b0, acc[1][0]);
            acc[1][1] = mfma16(a1, b1, acc[1][1]);
        }
        __syncthreads();
        if (it < 15) {
            int buf = (it + 1) & 1;
            if (Af) {
                half8 h0, h1;
                h0[0]=(half_t)pf0.x; h0[1]=(half_t)pf0.y; h0[2]=(half_t)pf0.z; h0[3]=(half_t)pf0.w;
                h0[4]=(half_t)pf1.x; h0[5]=(half_t)pf1.y; h0[6]=(half_t)pf1.z; h0[7]=(half_t)pf1.w;
                h1[0]=(half_t)pf2.x; h1[1]=(half_t)pf2.y; h1[2]=(half_t)pf2.z; h1[3]=(half_t)pf2.w;
                h1[4]=(half_t)pf3.x; h1[5]=(half_t)pf3.y; h1[6]=(half_t)pf3.z; h1[7]=(half_t)pf3.w;
                *(half8*)&As[buf][arow * 72 + acol] = h0;
                *(half8*)&As[buf][arow * 72 + acol + 8] = h1;
            } else {
                *(half8*)&As[buf][arow * 72 + acol] = ph0;
                *(half8*)&As[buf][arow * 72 + acol + 8] = ph1;
            }
            *(half8*)&Bs[buf][arow * 72 + acol] = pb0;
            *(half8*)&Bs[buf][arow * 72 + acol + 8] = pb1;
            __syncthreads();
        }
    }

    if (task == 0) {
        #pragma unroll
        for (int mi = 0; mi < 2; mi++)
            #pragma unroll
            for (int ni = 0; ni < 2; ni++)
                #pragma unroll
                for (int r = 0; r < 4; r++) {
                    int m = m0 + wm * 32 + mi * 16 + quad * 4 + r;
                    int n = n0 + wn * 32 + ni * 16 + lr;
                    qs_h[(size_t)m * 1024 + n] = (half_t)(acc[mi][ni][r] * 0.125f);
                }
    } else if (task == 2) {
        #pragma unroll
        for (int mi = 0; mi < 2; mi++)
            #pragma unroll
            for (int ni = 0; ni < 2; ni++)
                #pragma unroll
                for (int r = 0; r < 4; r++) {
                    int m = m0 + wm * 32 + mi * 16 + quad * 4 + r;
                    int n = n0 + wn * 32 + ni * 16 + lr;
                    out[(size_t)m * 1024 + n] = acc[mi][ni][r];
                }
    } else {
        // LDS-transpose epilogue: Ct[n_local][m_local], stride 68 floats
        __syncthreads();
        float* Ct = (float*)&As[0][0];
        #pragma unroll
        for (int mi = 0; mi < 2; mi++)
            #pragma unroll
            for (int ni = 0; ni < 2; ni++)
                #pragma unroll
                for (int r = 0; r < 4; r++)
                    Ct[(wn * 32 + ni * 16 + lr) * 68 + wm * 32 + mi * 16 + quad * 4 + r] = acc[mi][ni][r];
        __syncthreads();
        const int b = m0 >> 9, jm0 = m0 & 511;
        if (n0 < 256) {
            int gg = n0 >> 6;
            {   // out_k fp32: rows d, contiguous j (x4 head copies)
                int d = tid >> 2, jc = (tid & 3) * 16;
                float4 vv[4];
                #pragma unroll
                for (int u = 0; u < 4; u++) vv[u] = *(float4*)&Ct[d * 68 + jc + u * 4];
                #pragma unroll
                for (int t = 0; t < 4; t++)
                    #pragma unroll
                    for (int u = 0; u < 4; u++)
                        *(float4*)&out_k[((size_t)((b * 16 + gg * 4 + t) * 64 + d)) * 1536 + 1024 + jm0 + jc + u * 4] = vv[u];
            }
            {   // kp_h fp16: rows j, contiguous d
                int j = tid >> 2, dc = (tid & 3) * 16;
                half8 o0, o1;
                #pragma unroll
                for (int u = 0; u < 8; u++) o0[u] = (half_t)Ct[(dc + u) * 68 + j];
                #pragma unroll
                for (int u = 0; u < 8; u++) o1[u] = (half_t)Ct[(dc + 8 + u) * 68 + j];
                *(half8*)&kp_h[((size_t)(b * 512 + jm0 + j)) * 256 + n0 + dc] = o0;
                *(half8*)&kp_h[((size_t)(b * 512 + jm0 + j)) * 256 + n0 + dc + 8] = o1;
            }
        } else {
            int gg = (n0 - 256) >> 6;
            {   // out_v fp32: rows j, contiguous d (x4 head copies)
                int j = tid >> 2, dc = (tid & 3) * 16;
                float4 vv[4];
                #pragma unroll
                for (int u = 0; u < 4; u++) {
                    float4 x;
                    x.x = Ct[(dc + u * 4 + 0) * 68 + j];
                    x.y = Ct[(dc + u * 4 + 1) * 68 + j];
                    x.z = Ct[(dc + u * 4 + 2) * 68 + j];
                    x.w = Ct[(dc + u * 4 + 3) * 68 + j];
                    vv[u] = x;
                }
                #pragma unroll
                for (int t = 0; t < 4; t++)
                    #pragma unroll
                    for (int u = 0; u < 4; u++)
                        *(float4*)&out_v[(((size_t)(b * 16 + gg * 4 + t) * 1536) + 1024 + jm0 + j) * 64 + dc + u * 4] = vv[u];
            }
            {   // vpT fp16: rows d, contiguous j
                int d = tid >> 2, jc = (tid & 3) * 16;
                half8 o0, o1;
                #pragma unroll
                for (int u = 0; u < 8; u++) o0[u] = (half_t)Ct[d * 68 + jc + u];
                #pragma unroll
                for (int u = 0; u < 8; u++) o1[u] = (half_t)Ct[d * 68 + jc + 8 + u];
                *(half8*)&vpT[((size_t)((b * 4 + gg) * 64 + d)) * 512 + jm0 + jc] = o0;
                *(half8*)&vpT[((size_t)((b * 4 + gg) * 64 + d)) * 512 + jm0 + jc + 8] = o1;
            }
        }
    }
}

// ---------------------------------------------------------------------------
// Flash attention: per block = 64 Q-rows x one bh. Online softmax, fused
// rel-pos bias (bias GEMM in-block into LDS). j-tiles of 128 over Nk=2048.
// ---------------------------------------------------------------------------
__global__ __launch_bounds__(256) void flash(const half_t* __restrict__ qs_h,
                                             const half_t* __restrict__ Kc,
                                             const half_t* __restrict__ kp_h,
                                             const half_t* __restrict__ VcT,
                                             const half_t* __restrict__ vpT,
                                             const half_t* __restrict__ embc,
                                             half_t* __restrict__ AO)
{
    __shared__ __align__(16) half_t Qs[64 * 72];
    __shared__ __align__(16) half_t Ks[128 * 72];
    __shared__ __align__(16) half_t Vs[64 * 136];
    __shared__ __align__(16) half_t Ps[64 * 136];
    __shared__ half_t bt[64 * 322];
    const int bh = blockIdx.y, b = bh >> 4, h = bh & 15, g = h >> 2;
    const int i0 = blockIdx.x * 64;
    const int tid = threadIdx.x, w = tid >> 6, l = tid & 63;
    const int quad = l >> 4, lr = l & 15;

    {   // stage Q
        int row = tid >> 2, c = (tid & 3) * 16;
        const half_t* src = &qs_h[((size_t)(b * 512 + i0 + row)) * 1024 + h * 64 + c];
        *(half8*)&Qs[row * 72 + c]     = *(const half8*)src;
        *(half8*)&Qs[row * 72 + c + 8] = *(const half8*)(src + 8);
    }
    __syncthreads();

    // A-frags (Q rows w*16+lr), reused for bias GEMM and all S GEMMs
    half8 af0 = *(const half8*)&Qs[(w * 16 + lr) * 72 + quad * 8];
    half8 af1 = *(const half8*)&Qs[(w * 16 + lr) * 72 + 32 + quad * 8];

    // bias GEMM: bt[iw][t] = Q . embc^T  (t 0..319; B-frags from global embc)
    #pragma unroll 4
    for (int nf = 0; nf < 20; ++nf) {
        floatx4 acc = {0.f, 0.f, 0.f, 0.f};
        half8 b0 = *(const half8*)&embc[(size_t)(nf * 16 + lr) * 64 + quad * 8];
        half8 b1 = *(const half8*)&embc[(size_t)(nf * 16 + lr) * 64 + 32 + quad * 8];
        acc = mfma16(af0, b0, acc);
        acc = mfma16(af1, b1, acc);
        #pragma unroll
        for (int r = 0; r < 4; r++)
            bt[(w * 16 + quad * 4 + r) * 322 + nf * 16 + lr] = (half_t)acc[r];
    }
    __syncthreads();

    float bfv[4];
    int qtr[4];
    #pragma unroll
    for (int r = 0; r < 4; r++) {
        int f = ((quad & 1) * 4 + r) - (lr & 7) + 7;     // 0..14
        bfv[r] = (float)bt[(w * 16 + quad * 4 + r) * 322 + 256 + f];
        qtr[r] = (i0 + w * 16 + quad * 4 + r) >> 3;
    }

    floatx4 zero = {0.f, 0.f, 0.f, 0.f};
    floatx4 accO[4];
    #pragma unroll
    for (int ni = 0; ni < 4; ni++) accO[ni] = zero;
    float mrun[4] = {-1e30f, -1e30f, -1e30f, -1e30f};
    float lrun[4] = {0.f, 0.f, 0.f, 0.f};

    for (int jt = 0; jt < 16; ++jt) {
        const int j0 = jt * 128;
        __syncthreads();
        {   // stage K-tile (128 rows x 64)
            int row = tid >> 1, cb = (tid & 1) * 32;
            const half_t* src = (j0 < 1536)
                ? &Kc[((size_t)bh * 1536 + j0 + row) * 64 + cb]
                : &kp_h[((size_t)(b * 512 + j0 - 1536 + row)) * 256 + g * 64 + cb];
            #pragma unroll
            for (int u = 0; u < 4; u++)
                *(half8*)&Ks[row * 72 + cb + u * 8] = *(const half8*)(src + u * 8);
        }
        {   // stage V^T-tile (64 rows d x 128 j)
            int d = tid >> 2, cb = (tid & 3) * 32;
            const half_t* src = (j0 < 1536)
                ? &VcT[((size_t)bh * 64 + d) * 1536 + j0 + cb]
                : &vpT[((size_t)(b * 4 + g) * 64 + d) * 512 + (j0 - 1536) + cb];
            #pragma unroll
            for (int u = 0; u < 4; u++)
                *(half8*)&Vs[d * 136 + cb + u * 8] = *(const half8*)(src + u * 8);
        }
        __syncthreads();

        // S = Q . K^T (this wave's 16 rows x 128 cols)
        floatx4 s[8];
        #pragma unroll
        for (int nj = 0; nj < 8; nj++) {
            half8 b0 = *(const half8*)&Ks[(nj * 16 + lr) * 72 + quad * 8];
            half8 b1 = *(const half8*)&Ks[(nj * 16 + lr) * 72 + 32 + quad * 8];
            s[nj] = mfma16(af0, b0, zero);
            s[nj] = mfma16(af1, b1, s[nj]);
        }
        // bias add
        const int jtt = j0 >> 3;
        #pragma unroll
        for (int nj = 0; nj < 8; nj++)
            #pragma unroll
            for (int r = 0; r < 4; r++) {
                int t = 319 + qtr[r] - jtt - (nj * 2 + (lr >> 3));
                t = min(t, 254);
                s[nj][r] += (float)bt[(w * 16 + quad * 4 + r) * 322 + t] + bfv[r];
            }
        // online softmax
        float tmax[4];
        #pragma unroll
        for (int r = 0; r < 4; r++) {
            float tm = s[0][r];
            #pragma unroll
            for (int nj = 1; nj < 8; nj++) tm = fmaxf(tm, s[nj][r]);
            tm = fmaxf(tm, __shfl_xor(tm, 1));
            tm = fmaxf(tm, __shfl_xor(tm, 2));
            tm = fmaxf(tm, __shfl_xor(tm, 4));
            tm = fmaxf(tm, __shfl_xor(tm, 8));
            tmax[r] = tm;
        }
        float alpha[4];
        #pragma unroll
        for (int r = 0; r < 4; r++) {
            float mn = fmaxf(mrun[r], tmax[r]);
            alpha[r] = __expf(mrun[r] - mn);
            mrun[r] = mn;
        }
        float psum[4] = {0.f, 0.f, 0.f, 0.f};
        #pragma unroll
        for (int nj = 0; nj < 8; nj++)
            #pragma unroll
            for (int r = 0; r < 4; r++) {
                float p = __expf(s[nj][r] - mrun[r]);
                s[nj][r] = p;
                psum[r] += p;
            }
        #pragma unroll
        for (int r = 0; r < 4; r++) {
            float ps = psum[r];
            ps += __shfl_xor(ps, 1);
            ps += __shfl_xor(ps, 2);
            ps += __shfl_xor(ps, 4);
            ps += __shfl_xor(ps, 8);
            lrun[r] = lrun[r] * alpha[r] + ps;
        }
        #pragma unroll
        for (int ni = 0; ni < 4; ni++)
            #pragma unroll
            for (int r = 0; r < 4; r++) accO[ni][r] *= alpha[r];
        // P -> LDS (C-layout scatter)
        #pragma unroll
        for (int nj = 0; nj < 8; nj++)
            #pragma unroll
            for (int r = 0; r < 4; r++)
                Ps[(w * 16 + quad * 4 + r) * 136 + nj * 16 + lr] = (half_t)s[nj][r];
        __syncthreads();
        // PV accumulate
        #pragma unroll
        for (int ks = 0; ks < 4; ks++) {
            half8 pa = *(const half8*)&Ps[(w * 16 + lr) * 136 + ks * 32 + quad * 8];
            #pragma unroll
            for (int ni = 0; ni < 4; ni++) {
                half8 vb = *(const half8*)&Vs[(ni * 16 + lr) * 136 + ks * 32 + quad * 8];
                accO[ni] = mfma16(pa, vb, accO[ni]);
            }
        }
    }

    float inv[4];
    #pragma unroll
    for (int r = 0; r < 4; r++) inv[r] = 1.0f / lrun[r];
    #pragma unroll
    for (int ni = 0; ni < 4; ni++)
        #pragma unroll
        for (int r = 0; r < 4; r++) {
            int i = i0 + w * 16 + quad * 4 + r;
            AO[((size_t)(b * 512 + i)) * 1024 + h * 64 + ni * 16 + lr] =
                (half_t)(accO[ni][r] * inv[r]);
        }
}

// ---------------------------------------------------------------------------
extern "C" void kernel_launch(void* const* d_in, const int* in_sizes, int n_in,
                              void* d_out, int out_size, void* d_ws, size_t ws_size,
                              hipStream_t stream)
{
    const float* q       = (const float*)d_in[0];
    const float* k       = (const float*)d_in[1];
    const float* v       = (const float*)d_in[2];
    const float* cache_k = (const float*)d_in[3];
    const float* cache_v = (const float*)d_in[4];
    const float* Wq      = (const float*)d_in[5];
    const float* Wk      = (const float*)d_in[6];
    const float* Wv      = (const float*)d_in[7];
    const float* Wo      = (const float*)d_in[8];
    const float* emb_t   = (const float*)d_in[9];
    const float* emb_f   = (const float*)d_in[10];

    float* out   = (float*)d_out;                 // (2,512,1024)
    float* out_k = out + 1048576;                 // (32,64,1536)
    float* out_v = out_k + 3145728;               // (32,1536,64)

    half_t* ws = (half_t*)d_ws;
    half_t* qs_h = ws;                  // 1048576
    half_t* kp_h = ws + 1048576;        //  262144
    half_t* vpT  = ws + 1310720;        //  262144
    half_t* Kc   = ws + 1572864;        // 3145728
    half_t* VcT  = ws + 4718592;        // 3145728
    half_t* WqT  = ws + 7864320;        // 1048576
    half_t* WkvT = ws + 8912896;        //  524288
    half_t* WoT  = ws + 9437184;        // 1048576
    half_t* embc = ws + 10485760;       //   20480
    half_t* AO   = ws + 10506240;       // 1048576

    wtrans<<<dim3(16, 16, 5), 256, 0, stream>>>(Wq, Wk, Wv, Wo, emb_t, emb_f,
                                                WqT, WkvT, WoT, embc);
    tc_kv<<<dim3(24, 32, 2), 256, 0, stream>>>(cache_k, cache_v, Kc, VcT, out_k, out_v);
    proj<<<dim3(384), 256, 0, stream>>>(0, q, k, v, nullptr, WqT, WkvT, WoT,
                                        qs_h, kp_h, vpT, out, out_k, out_v);
    flash<<<dim3(8, 32), 256, 0, stream>>>(qs_h, Kc, kp_h, VcT, vpT, embc, AO);
    proj<<<dim3(256), 256, 0, stream>>>(1, q, k, v, AO, WqT, WkvT, WoT,
                                        qs_h, kp_h, vpT, out, out_k, out_v);
}

// Round 4
// 197.954 us; speedup vs baseline: 6.4624x; 1.0681x over previous
//
#include <hip/hip_runtime.h>
#include <math.h>

typedef _Float16 half_t;
typedef _Float16 half8  __attribute__((ext_vector_type(8)));
typedef float    floatx4 __attribute__((ext_vector_type(4)));

static __device__ __forceinline__ floatx4 mfma16(half8 a, half8 b, floatx4 c) {
    return __builtin_amdgcn_mfma_f32_16x16x32_f16(a, b, c, 0, 0, 0);
}

// ---------------------------------------------------------------------------
// prep: merged cache transpose-converts (+fused fp32 cache-shift copies),
// weight transpose-converts, and embc build.
// z=0: cache_k -> Kc [bh][j][d] fp16 ; out_k[j<1024] fp32
// z=1: cache_v -> VcT [bh][d][j] fp16 ; out_v[j<1024] fp32
// z=2: W transposes (flattened id) + embc
// ---------------------------------------------------------------------------
__global__ __launch_bounds__(256) void prep(const float* __restrict__ cache_k,
                                            const float* __restrict__ cache_v,
                                            const float* __restrict__ Wq,
                                            const float* __restrict__ Wk,
                                            const float* __restrict__ Wv,
                                            const float* __restrict__ Wo,
                                            const float* __restrict__ emb_t,
                                            const float* __restrict__ emb_f,
                                            half_t* __restrict__ Kc,
                                            half_t* __restrict__ VcT,
                                            float* __restrict__ out_k,
                                            float* __restrict__ out_v,
                                            half_t* __restrict__ WqT,
                                            half_t* __restrict__ WkvT,
                                            half_t* __restrict__ WoT,
                                            half_t* __restrict__ embc)
{
    const int tid = threadIdx.x;
    const int z = blockIdx.z;
    __shared__ float t[64][65];
    if (z == 0) {
        const int bh = blockIdx.y, j0 = blockIdx.x * 64;
        for (int idx = tid; idx < 4096; idx += 256) {
            int d = idx >> 6, jj = idx & 63;
            float v = cache_k[((size_t)bh * 64 + d) * 1536 + j0 + jj];
            t[d][jj] = v;
            int js = j0 + jj;
            if (js >= 512) out_k[((size_t)bh * 64 + d) * 1536 + js - 512] = v;
        }
        __syncthreads();
        for (int idx = tid; idx < 4096; idx += 256) {
            int jj = idx >> 6, d = idx & 63;
            Kc[((size_t)bh * 1536 + j0 + jj) * 64 + d] = (half_t)t[d][jj];
        }
    } else if (z == 1) {
        const int bh = blockIdx.y, j0 = blockIdx.x * 64;
        for (int idx = tid; idx < 4096; idx += 256) {
            int jj = idx >> 6, d = idx & 63;
            float v = cache_v[((size_t)bh * 1536 + j0 + jj) * 64 + d];
            t[jj][d] = v;
            if (j0 + jj >= 512) out_v[((size_t)bh * 1536 + j0 + jj - 512) * 64 + d] = v;
        }
        __syncthreads();
        for (int idx = tid; idx < 4096; idx += 256) {
            int d = idx >> 6, jj = idx & 63;
            VcT[((size_t)bh * 64 + d) * 1536 + j0 + jj] = (half_t)t[jj][d];
        }
    } else {
        const int id = blockIdx.y * 24 + blockIdx.x;
        const float* src; half_t* dst; int Ncols, n0, k0;
        if (id < 256)      { src = Wq; dst = WqT; Ncols = 1024; n0 = (id & 15) * 64; k0 = (id >> 4) * 64; }
        else if (id < 320) { int q2 = id - 256; src = Wk; dst = WkvT; Ncols = 256; n0 = (q2 & 3) * 64; k0 = (q2 >> 2) * 64; }
        else if (id < 384) { int q2 = id - 320; src = Wv; dst = WkvT + 256 * 1024; Ncols = 256; n0 = (q2 & 3) * 64; k0 = (q2 >> 2) * 64; }
        else if (id < 640) { int q2 = id - 384; src = Wo; dst = WoT; Ncols = 1024; n0 = (q2 & 15) * 64; k0 = (q2 >> 4) * 64; }
        else if (id < 720) {
            int idx = (id - 640) * 256 + tid;
            int row = idx >> 6, col = idx & 63;
            float val = 0.f;
            if (row < 255) val = emb_t[row * 64 + col];
            else if (row >= 256 && row < 271) val = emb_f[(row - 256) * 64 + col];
            embc[idx] = (half_t)val;
            return;
        } else return;
        for (int idx = tid; idx < 4096; idx += 256) {
            int r = idx >> 6, cc = idx & 63;
            t[r][cc] = src[(size_t)(k0 + r) * Ncols + n0 + cc];
        }
        __syncthreads();
        for (int idx = tid; idx < 4096; idx += 256) {
            int r = idx >> 6, cc = idx & 63;
            dst[(size_t)(n0 + r) * 1024 + k0 + cc] = (half_t)t[cc][r];
        }
    }
}

// ---------------------------------------------------------------------------
// Unified projection GEMM: 64x64 tile, BK=64, double-buffered, 4 waves (2x2,
// each 32x32). phase 0: blocks 0..255 = q-proj (fp16 out, x0.125),
// 256..383 = k/v-proj (LDS-transpose epilogue -> kp_h/vpT fp16 + out_k/out_v
// fp32 new regions). phase 1: out-proj (A = AO fp16, fp32 out).
// ---------------------------------------------------------------------------
__global__ __launch_bounds__(256) void proj(int phase,
                                            const float* __restrict__ qin,
                                            const float* __restrict__ kin,
                                            const float* __restrict__ vin,
                                            const half_t* __restrict__ AO,
                                            const half_t* __restrict__ WqT,
                                            const half_t* __restrict__ WkvT,
                                            const half_t* __restrict__ WoT,
                                            half_t* __restrict__ qs_h,
                                            half_t* __restrict__ kp_h,
                                            half_t* __restrict__ vpT,
                                            float* __restrict__ out,
                                            float* __restrict__ out_k,
                                            float* __restrict__ out_v)
{
    __shared__ __align__(16) half_t As[2][64 * 72];
    __shared__ __align__(16) half_t Bs[2][64 * 72];
    const int id = blockIdx.x;
    int task, m0, n0;
    const float* Af = nullptr; const half_t* Ah = nullptr; const half_t* Bt;
    if (phase == 1)      { task = 2; m0 = (id >> 4) * 64; n0 = (id & 15) * 64; Ah = AO; Bt = WoT; }
    else if (id < 256)   { task = 0; m0 = (id >> 4) * 64; n0 = (id & 15) * 64; Af = qin; Bt = WqT; }
    else { task = 1; int t = id - 256; m0 = (t >> 3) * 64; n0 = (t & 7) * 64;
           Af = (n0 < 256) ? kin : vin; Bt = WkvT; }

    const int tid = threadIdx.x, w = tid >> 6, l = tid & 63;
    const int quad = l >> 4, lr = l & 15, wm = w >> 1, wn = w & 1;
    const int arow = tid >> 2, acol = (tid & 3) * 16;

    // stage tile 0
    {
        if (Af) {
            float4 f0 = *(const float4*)&Af[(size_t)(m0 + arow) * 1024 + acol];
            float4 f1 = *(const float4*)&Af[(size_t)(m0 + arow) * 1024 + acol + 4];
            float4 f2 = *(const float4*)&Af[(size_t)(m0 + arow) * 1024 + acol + 8];
            float4 f3 = *(const float4*)&Af[(size_t)(m0 + arow) * 1024 + acol + 12];
            half8 h0, h1;
            h0[0]=(half_t)f0.x; h0[1]=(half_t)f0.y; h0[2]=(half_t)f0.z; h0[3]=(half_t)f0.w;
            h0[4]=(half_t)f1.x; h0[5]=(half_t)f1.y; h0[6]=(half_t)f1.z; h0[7]=(half_t)f1.w;
            h1[0]=(half_t)f2.x; h1[1]=(half_t)f2.y; h1[2]=(half_t)f2.z; h1[3]=(half_t)f2.w;
            h1[4]=(half_t)f3.x; h1[5]=(half_t)f3.y; h1[6]=(half_t)f3.z; h1[7]=(half_t)f3.w;
            *(half8*)&As[0][arow * 72 + acol] = h0;
            *(half8*)&As[0][arow * 72 + acol + 8] = h1;
        } else {
            *(half8*)&As[0][arow * 72 + acol]     = *(const half8*)&Ah[(size_t)(m0 + arow) * 1024 + acol];
            *(half8*)&As[0][arow * 72 + acol + 8] = *(const half8*)&Ah[(size_t)(m0 + arow) * 1024 + acol + 8];
        }
        *(half8*)&Bs[0][arow * 72 + acol]     = *(const half8*)&Bt[(size_t)(n0 + arow) * 1024 + acol];
        *(half8*)&Bs[0][arow * 72 + acol + 8] = *(const half8*)&Bt[(size_t)(n0 + arow) * 1024 + acol + 8];
    }
    __syncthreads();

    floatx4 zero = {0.f, 0.f, 0.f, 0.f};
    floatx4 acc[2][2];
    acc[0][0] = zero; acc[0][1] = zero; acc[1][0] = zero; acc[1][1] = zero;

    float4 pf0, pf1, pf2, pf3; half8 ph0, ph1, pb0, pb1;
    for (int it = 0; it < 16; ++it) {
        if (it < 15) {
            int kk = (it + 1) * 64;
            if (Af) {
                pf0 = *(const float4*)&Af[(size_t)(m0 + arow) * 1024 + kk + acol];
                pf1 = *(const float4*)&Af[(size_t)(m0 + arow) * 1024 + kk + acol + 4];
                pf2 = *(const float4*)&Af[(size_t)(m0 + arow) * 1024 + kk + acol + 8];
                pf3 = *(const float4*)&Af[(size_t)(m0 + arow) * 1024 + kk + acol + 12];
            } else {
                ph0 = *(const half8*)&Ah[(size_t)(m0 + arow) * 1024 + kk + acol];
                ph1 = *(const half8*)&Ah[(size_t)(m0 + arow) * 1024 + kk + acol + 8];
            }
            pb0 = *(const half8*)&Bt[(size_t)(n0 + arow) * 1024 + kk + acol];
            pb1 = *(const half8*)&Bt[(size_t)(n0 + arow) * 1024 + kk + acol + 8];
        }
        const half_t* Ab = &As[it & 1][0];
        const half_t* Bb = &Bs[it & 1][0];
        #pragma unroll
        for (int ks = 0; ks < 2; ++ks) {
            half8 a0 = *(const half8*)&Ab[(wm * 32 + lr) * 72 + ks * 32 + quad * 8];
            half8 a1 = *(const half8*)&Ab[(wm * 32 + 16 + lr) * 72 + ks * 32 + quad * 8];
            half8 b0 = *(const half8*)&Bb[(wn * 32 + lr) * 72 + ks * 32 + quad * 8];
            half8 b1 = *(const half8*)&Bb[(wn * 32 + 16 + lr) * 72 + ks * 32 + quad * 8];
            acc[0][0] = mfma16(a0, b0, acc[0][0]);
            acc[0][1] = mfma16(a0, b1, acc[0][1]);
            acc[1][0] = mfma16(a1, b0, acc[1][0]);
            acc[1][1] = mfma16(a1, b1, acc[1][1]);
        }
        __syncthreads();
        if (it < 15) {
            int buf = (it + 1) & 1;
            if (Af) {
                half8 h0, h1;
                h0[0]=(half_t)pf0.x; h0[1]=(half_t)pf0.y; h0[2]=(half_t)pf0.z; h0[3]=(half_t)pf0.w;
                h0[4]=(half_t)pf1.x; h0[5]=(half_t)pf1.y; h0[6]=(half_t)pf1.z; h0[7]=(half_t)pf1.w;
                h1[0]=(half_t)pf2.x; h1[1]=(half_t)pf2.y; h1[2]=(half_t)pf2.z; h1[3]=(half_t)pf2.w;
                h1[4]=(half_t)pf3.x; h1[5]=(half_t)pf3.y; h1[6]=(half_t)pf3.z; h1[7]=(half_t)pf3.w;
                *(half8*)&As[buf][arow * 72 + acol] = h0;
                *(half8*)&As[buf][arow * 72 + acol + 8] = h1;
            } else {
                *(half8*)&As[buf][arow * 72 + acol] = ph0;
                *(half8*)&As[buf][arow * 72 + acol + 8] = ph1;
            }
            *(half8*)&Bs[buf][arow * 72 + acol] = pb0;
            *(half8*)&Bs[buf][arow * 72 + acol + 8] = pb1;
            __syncthreads();
        }
    }

    if (task == 0) {
        #pragma unroll
        for (int mi = 0; mi < 2; mi++)
            #pragma unroll
            for (int ni = 0; ni < 2; ni++)
                #pragma unroll
                for (int r = 0; r < 4; r++) {
                    int m = m0 + wm * 32 + mi * 16 + quad * 4 + r;
                    int n = n0 + wn * 32 + ni * 16 + lr;
                    qs_h[(size_t)m * 1024 + n] = (half_t)(acc[mi][ni][r] * 0.125f);
                }
    } else if (task == 2) {
        #pragma unroll
        for (int mi = 0; mi < 2; mi++)
            #pragma unroll
            for (int ni = 0; ni < 2; ni++)
                #pragma unroll
                for (int r = 0; r < 4; r++) {
                    int m = m0 + wm * 32 + mi * 16 + quad * 4 + r;
                    int n = n0 + wn * 32 + ni * 16 + lr;
                    out[(size_t)m * 1024 + n] = acc[mi][ni][r];
                }
    } else {
        __syncthreads();
        float* Ct = (float*)&As[0][0];
        #pragma unroll
        for (int mi = 0; mi < 2; mi++)
            #pragma unroll
            for (int ni = 0; ni < 2; ni++)
                #pragma unroll
                for (int r = 0; r < 4; r++)
                    Ct[(wn * 32 + ni * 16 + lr) * 68 + wm * 32 + mi * 16 + quad * 4 + r] = acc[mi][ni][r];
        __syncthreads();
        const int b = m0 >> 9, jm0 = m0 & 511;
        if (n0 < 256) {
            int gg = n0 >> 6;
            {
                int d = tid >> 2, jc = (tid & 3) * 16;
                float4 vv[4];
                #pragma unroll
                for (int u = 0; u < 4; u++) vv[u] = *(float4*)&Ct[d * 68 + jc + u * 4];
                #pragma unroll
                for (int t = 0; t < 4; t++)
                    #pragma unroll
                    for (int u = 0; u < 4; u++)
                        *(float4*)&out_k[((size_t)((b * 16 + gg * 4 + t) * 64 + d)) * 1536 + 1024 + jm0 + jc + u * 4] = vv[u];
            }
            {
                int j = tid >> 2, dc = (tid & 3) * 16;
                half8 o0, o1;
                #pragma unroll
                for (int u = 0; u < 8; u++) o0[u] = (half_t)Ct[(dc + u) * 68 + j];
                #pragma unroll
                for (int u = 0; u < 8; u++) o1[u] = (half_t)Ct[(dc + 8 + u) * 68 + j];
                *(half8*)&kp_h[((size_t)(b * 512 + jm0 + j)) * 256 + n0 + dc] = o0;
                *(half8*)&kp_h[((size_t)(b * 512 + jm0 + j)) * 256 + n0 + dc + 8] = o1;
            }
        } else {
            int gg = (n0 - 256) >> 6;
            {
                int j = tid >> 2, dc = (tid & 3) * 16;
                float4 vv[4];
                #pragma unroll
                for (int u = 0; u < 4; u++) {
                    float4 x;
                    x.x = Ct[(dc + u * 4 + 0) * 68 + j];
                    x.y = Ct[(dc + u * 4 + 1) * 68 + j];
                    x.z = Ct[(dc + u * 4 + 2) * 68 + j];
                    x.w = Ct[(dc + u * 4 + 3) * 68 + j];
                    vv[u] = x;
                }
                #pragma unroll
                for (int t = 0; t < 4; t++)
                    #pragma unroll
                    for (int u = 0; u < 4; u++)
                        *(float4*)&out_v[(((size_t)(b * 16 + gg * 4 + t) * 1536) + 1024 + jm0 + j) * 64 + dc + u * 4] = vv[u];
            }
            {
                int d = tid >> 2, jc = (tid & 3) * 16;
                half8 o0, o1;
                #pragma unroll
                for (int u = 0; u < 8; u++) o0[u] = (half_t)Ct[d * 68 + jc + u];
                #pragma unroll
                for (int u = 0; u < 8; u++) o1[u] = (half_t)Ct[d * 68 + jc + 8 + u];
                *(half8*)&vpT[((size_t)((b * 4 + gg) * 64 + d)) * 512 + jm0 + jc] = o0;
                *(half8*)&vpT[((size_t)((b * 4 + gg) * 64 + d)) * 512 + jm0 + jc + 8] = o1;
            }
        }
    }
}

// ---------------------------------------------------------------------------
// Flash attention v2: register-prefetched K/V tiles, 2 barriers per j-tile.
// Per block = 64 Q-rows x one bh; wave-private P/bt LDS regions.
// ---------------------------------------------------------------------------
__global__ __launch_bounds__(256) void flash(const half_t* __restrict__ qs_h,
                                             const half_t* __restrict__ Kc,
                                             const half_t* __restrict__ kp_h,
                                             const half_t* __restrict__ VcT,
                                             const half_t* __restrict__ vpT,
                                             const half_t* __restrict__ embc,
                                             half_t* __restrict__ AO)
{
    __shared__ __align__(16) half_t Qs[64 * 72];
    __shared__ __align__(16) half_t Ks[128 * 72];
    __shared__ __align__(16) half_t Vs[64 * 136];
    __shared__ __align__(16) half_t Ps[64 * 136];
    __shared__ half_t bt[64 * 322];
    const int bh = blockIdx.y, b = bh >> 4, h = bh & 15, g = h >> 2;
    const int i0 = blockIdx.x * 64;
    const int tid = threadIdx.x, w = tid >> 6, l = tid & 63;
    const int quad = l >> 4, lr = l & 15;

    {   // stage Q
        int row = tid >> 2, c = (tid & 3) * 16;
        const half_t* src = &qs_h[((size_t)(b * 512 + i0 + row)) * 1024 + h * 64 + c];
        *(half8*)&Qs[row * 72 + c]     = *(const half8*)src;
        *(half8*)&Qs[row * 72 + c + 8] = *(const half8*)(src + 8);
    }

    const int krow = tid >> 1, kcb = (tid & 1) * 32;
    const int vd = tid >> 2, vcb = (tid & 3) * 32;
    half8 kr[4], vr[4];
    {   // preload tile 0 (j0 = 0 < 1536)
        const half_t* ksrc = &Kc[((size_t)bh * 1536 + krow) * 64 + kcb];
        const half_t* vsrc = &VcT[((size_t)bh * 64 + vd) * 1536 + vcb];
        #pragma unroll
        for (int u = 0; u < 4; u++) kr[u] = *(const half8*)(ksrc + u * 8);
        #pragma unroll
        for (int u = 0; u < 4; u++) vr[u] = *(const half8*)(vsrc + u * 8);
    }
    __syncthreads();   // Qs ready

    half8 af0 = *(const half8*)&Qs[(w * 16 + lr) * 72 + quad * 8];
    half8 af1 = *(const half8*)&Qs[(w * 16 + lr) * 72 + 32 + quad * 8];

    floatx4 zero = {0.f, 0.f, 0.f, 0.f};
    // bias GEMM into bt (wave-private rows, no barrier needed)
    #pragma unroll 4
    for (int nf = 0; nf < 20; ++nf) {
        floatx4 acc = zero;
        half8 b0 = *(const half8*)&embc[(size_t)(nf * 16 + lr) * 64 + quad * 8];
        half8 b1 = *(const half8*)&embc[(size_t)(nf * 16 + lr) * 64 + 32 + quad * 8];
        acc = mfma16(af0, b0, acc);
        acc = mfma16(af1, b1, acc);
        #pragma unroll
        for (int r = 0; r < 4; r++)
            bt[(w * 16 + quad * 4 + r) * 322 + nf * 16 + lr] = (half_t)acc[r];
    }

    // write tile-0 K/V to LDS
    #pragma unroll
    for (int u = 0; u < 4; u++) *(half8*)&Ks[krow * 72 + kcb + u * 8] = kr[u];
    #pragma unroll
    for (int u = 0; u < 4; u++) *(half8*)&Vs[vd * 136 + vcb + u * 8] = vr[u];
    __syncthreads();

    float bfv[4];
    int qtr[4];
    #pragma unroll
    for (int r = 0; r < 4; r++) {
        int f = ((quad & 1) * 4 + r) - (lr & 7) + 7;     // 0..14
        bfv[r] = (float)bt[(w * 16 + quad * 4 + r) * 322 + 256 + f];
        qtr[r] = (i0 + w * 16 + quad * 4 + r) >> 3;
    }

    floatx4 accO[4];
    #pragma unroll
    for (int ni = 0; ni < 4; ni++) accO[ni] = zero;
    float mrun[4] = {-1e30f, -1e30f, -1e30f, -1e30f};
    float lrun[4] = {0.f, 0.f, 0.f, 0.f};

    for (int jt = 0; jt < 16; ++jt) {
        // prefetch next K/V tile into registers (overlaps with compute below)
        if (jt < 15) {
            const int j1 = (jt + 1) * 128;
            const half_t* ksrc = (j1 < 1536)
                ? &Kc[((size_t)bh * 1536 + j1 + krow) * 64 + kcb]
                : &kp_h[((size_t)(b * 512 + j1 - 1536 + krow)) * 256 + g * 64 + kcb];
            const half_t* vsrc = (j1 < 1536)
                ? &VcT[((size_t)bh * 64 + vd) * 1536 + j1 + vcb]
                : &vpT[((size_t)(b * 4 + g) * 64 + vd) * 512 + (j1 - 1536) + vcb];
            #pragma unroll
            for (int u = 0; u < 4; u++) kr[u] = *(const half8*)(ksrc + u * 8);
            #pragma unroll
            for (int u = 0; u < 4; u++) vr[u] = *(const half8*)(vsrc + u * 8);
        }

        // S = Q . K^T (this wave's 16 rows x 128 cols)
        floatx4 s[8];
        #pragma unroll
        for (int nj = 0; nj < 8; nj++) {
            half8 b0 = *(const half8*)&Ks[(nj * 16 + lr) * 72 + quad * 8];
            half8 b1 = *(const half8*)&Ks[(nj * 16 + lr) * 72 + 32 + quad * 8];
            s[nj] = mfma16(af0, b0, zero);
            s[nj] = mfma16(af1, b1, s[nj]);
        }
        // bias add
        const int jtt = jt * 16;
        #pragma unroll
        for (int nj = 0; nj < 8; nj++)
            #pragma unroll
            for (int r = 0; r < 4; r++) {
                int t = 319 + qtr[r] - jtt - (nj * 2 + (lr >> 3));
                t = min(t, 254);
                s[nj][r] += (float)bt[(w * 16 + quad * 4 + r) * 322 + t] + bfv[r];
            }
        // online softmax
        float tmax[4];
        #pragma unroll
        for (int r = 0; r < 4; r++) {
            float tm = s[0][r];
            #pragma unroll
            for (int nj = 1; nj < 8; nj++) tm = fmaxf(tm, s[nj][r]);
            tm = fmaxf(tm, __shfl_xor(tm, 1));
            tm = fmaxf(tm, __shfl_xor(tm, 2));
            tm = fmaxf(tm, __shfl_xor(tm, 4));
            tm = fmaxf(tm, __shfl_xor(tm, 8));
            tmax[r] = tm;
        }
        float alpha[4];
        #pragma unroll
        for (int r = 0; r < 4; r++) {
            float mn = fmaxf(mrun[r], tmax[r]);
            alpha[r] = __expf(mrun[r] - mn);
            mrun[r] = mn;
        }
        float psum[4] = {0.f, 0.f, 0.f, 0.f};
        #pragma unroll
        for (int nj = 0; nj < 8; nj++)
            #pragma unroll
            for (int r = 0; r < 4; r++) {
                float p = __expf(s[nj][r] - mrun[r]);
                s[nj][r] = p;
                psum[r] += p;
            }
        #pragma unroll
        for (int r = 0; r < 4; r++) {
            float ps = psum[r];
            ps += __shfl_xor(ps, 1);
            ps += __shfl_xor(ps, 2);
            ps += __shfl_xor(ps, 4);
            ps += __shfl_xor(ps, 8);
            lrun[r] = lrun[r] * alpha[r] + ps;
        }
        #pragma unroll
        for (int ni = 0; ni < 4; ni++)
            #pragma unroll
            for (int r = 0; r < 4; r++) accO[ni][r] *= alpha[r];
        // P -> LDS (wave-private rows; in-order DS pipe makes readback safe)
        #pragma unroll
        for (int nj = 0; nj < 8; nj++)
            #pragma unroll
            for (int r = 0; r < 4; r++)
                Ps[(w * 16 + quad * 4 + r) * 136 + nj * 16 + lr] = (half_t)s[nj][r];
        // PV accumulate
        #pragma unroll
        for (int ks = 0; ks < 4; ks++) {
            half8 pa = *(const half8*)&Ps[(w * 16 + lr) * 136 + ks * 32 + quad * 8];
            #pragma unroll
            for (int ni = 0; ni < 4; ni++) {
                half8 vb = *(const half8*)&Vs[(ni * 16 + lr) * 136 + ks * 32 + quad * 8];
                accO[ni] = mfma16(pa, vb, accO[ni]);
            }
        }
        __syncthreads();   // all waves done reading Ks/Vs
        if (jt < 15) {
            #pragma unroll
            for (int u = 0; u < 4; u++) *(half8*)&Ks[krow * 72 + kcb + u * 8] = kr[u];
            #pragma unroll
            for (int u = 0; u < 4; u++) *(half8*)&Vs[vd * 136 + vcb + u * 8] = vr[u];
            __syncthreads();
        }
    }

    float inv[4];
    #pragma unroll
    for (int r = 0; r < 4; r++) inv[r] = 1.0f / lrun[r];
    #pragma unroll
    for (int ni = 0; ni < 4; ni++)
        #pragma unroll
        for (int r = 0; r < 4; r++) {
            int i = i0 + w * 16 + quad * 4 + r;
            AO[((size_t)(b * 512 + i)) * 1024 + h * 64 + ni * 16 + lr] =
                (half_t)(accO[ni][r] * inv[r]);
        }
}

// ---------------------------------------------------------------------------
extern "C" void kernel_launch(void* const* d_in, const int* in_sizes, int n_in,
                              void* d_out, int out_size, void* d_ws, size_t ws_size,
                              hipStream_t stream)
{
    const float* q       = (const float*)d_in[0];
    const float* k       = (const float*)d_in[1];
    const float* v       = (const float*)d_in[2];
    const float* cache_k = (const float*)d_in[3];
    const float* cache_v = (const float*)d_in[4];
    const float* Wq      = (const float*)d_in[5];
    const float* Wk      = (const float*)d_in[6];
    const float* Wv      = (const float*)d_in[7];
    const float* Wo      = (const float*)d_in[8];
    const float* emb_t   = (const float*)d_in[9];
    const float* emb_f   = (const float*)d_in[10];

    float* out   = (float*)d_out;                 // (2,512,1024)
    float* out_k = out + 1048576;                 // (32,64,1536)
    float* out_v = out_k + 3145728;               // (32,1536,64)

    half_t* ws = (half_t*)d_ws;
    half_t* qs_h = ws;                  // 1048576
    half_t* kp_h = ws + 1048576;        //  262144
    half_t* vpT  = ws + 1310720;        //  262144
    half_t* Kc   = ws + 1572864;        // 3145728
    half_t* VcT  = ws + 4718592;        // 3145728
    half_t* WqT  = ws + 7864320;        // 1048576
    half_t* WkvT = ws + 8912896;        //  524288
    half_t* WoT  = ws + 9437184;        // 1048576
    half_t* embc = ws + 10485760;       //   20480
    half_t* AO   = ws + 10506240;       // 1048576

    prep<<<dim3(24, 32, 3), 256, 0, stream>>>(cache_k, cache_v, Wq, Wk, Wv, Wo,
                                              emb_t, emb_f, Kc, VcT, out_k, out_v,
                                              WqT, WkvT, WoT, embc);
    proj<<<dim3(384), 256, 0, stream>>>(0, q, k, v, nullptr, WqT, WkvT, WoT,
                                        qs_h, kp_h, vpT, out, out_k, out_v);
    flash<<<dim3(8, 32), 256, 0, stream>>>(qs_h, Kc, kp_h, VcT, vpT, embc, AO);
    proj<<<dim3(256), 256, 0, stream>>>(1, q, k, v, AO, WqT, WkvT, WoT,
                                        qs_h, kp_h, vpT, out, out_k, out_v);
}

// Round 5
// 181.439 us; speedup vs baseline: 7.0506x; 1.0910x over previous
//
#include <hip/hip_runtime.h>
#include <math.h>

typedef _Float16 half_t;
typedef _Float16 half8  __attribute__((ext_vector_type(8)));
typedef float    floatx4 __attribute__((ext_vector_type(4)));

#define LOG2E 1.44269504088896f

static __device__ __forceinline__ floatx4 mfma16(half8 a, half8 b, floatx4 c) {
    return __builtin_amdgcn_mfma_f32_16x16x32_f16(a, b, c, 0, 0, 0);
}

// ---------------------------------------------------------------------------
// prep (256 thr): z=0 cache_k -> Kc[bh][j][d] fp16 + out_k shift fp32
//                 z=1 cache_v -> VcT[bh][d][j] fp16 + out_v shift fp32
//                 z=2 weight transposes + embc build. All float4 loads.
// ---------------------------------------------------------------------------
__global__ __launch_bounds__(256) void prep(const float* __restrict__ cache_k,
                                            const float* __restrict__ cache_v,
                                            const float* __restrict__ Wq,
                                            const float* __restrict__ Wk,
                                            const float* __restrict__ Wv,
                                            const float* __restrict__ Wo,
                                            const float* __restrict__ emb_t,
                                            const float* __restrict__ emb_f,
                                            half_t* __restrict__ Kc,
                                            half_t* __restrict__ VcT,
                                            float* __restrict__ out_k,
                                            float* __restrict__ out_v,
                                            half_t* __restrict__ WqT,
                                            half_t* __restrict__ WkvT,
                                            half_t* __restrict__ WoT,
                                            half_t* __restrict__ embc)
{
    const int tid = threadIdx.x;
    const int z = blockIdx.z;
    __shared__ float t[64][65];
    if (z == 0) {
        const int bh = blockIdx.y, j0 = blockIdx.x * 64;
        const bool shift = (j0 >= 512);
        #pragma unroll
        for (int i2 = 0; i2 < 4; i2++) {
            int idx = i2 * 256 + tid;
            int d = idx >> 4, j4 = (idx & 15) * 4;
            float4 vv = *(const float4*)&cache_k[((size_t)bh * 64 + d) * 1536 + j0 + j4];
            *(float4*)&t[d][j4] = vv;
            if (shift) *(float4*)&out_k[((size_t)bh * 64 + d) * 1536 + j0 - 512 + j4] = vv;
        }
        __syncthreads();
        #pragma unroll
        for (int i2 = 0; i2 < 2; i2++) {
            int idx = i2 * 256 + tid;
            int j = idx >> 3, db = (idx & 7) * 8;
            half8 o;
            #pragma unroll
            for (int u = 0; u < 8; u++) o[u] = (half_t)t[db + u][j];
            *(half8*)&Kc[((size_t)bh * 1536 + j0 + j) * 64 + db] = o;
        }
    } else if (z == 1) {
        const int bh = blockIdx.y, j0 = blockIdx.x * 64;
        const bool shift = (j0 >= 512);
        #pragma unroll
        for (int i2 = 0; i2 < 4; i2++) {
            int idx = i2 * 256 + tid;
            int j = idx >> 4, d4 = (idx & 15) * 4;
            float4 vv = *(const float4*)&cache_v[((size_t)bh * 1536 + j0 + j) * 64 + d4];
            *(float4*)&t[j][d4] = vv;
            if (shift) *(float4*)&out_v[((size_t)bh * 1536 + j0 + j - 512) * 64 + d4] = vv;
        }
        __syncthreads();
        #pragma unroll
        for (int i2 = 0; i2 < 2; i2++) {
            int idx = i2 * 256 + tid;
            int d = idx >> 3, jb = (idx & 7) * 8;
            half8 o;
            #pragma unroll
            for (int u = 0; u < 8; u++) o[u] = (half_t)t[jb + u][d];
            *(half8*)&VcT[((size_t)bh * 64 + d) * 1536 + j0 + jb] = o;
        }
    } else {
        const int id = blockIdx.y * 24 + blockIdx.x;
        const float* src; half_t* dst; int Ncols, n0, k0;
        if (id < 256)      { src = Wq; dst = WqT; Ncols = 1024; n0 = (id & 15) * 64; k0 = (id >> 4) * 64; }
        else if (id < 320) { int q2 = id - 256; src = Wk; dst = WkvT; Ncols = 256; n0 = (q2 & 3) * 64; k0 = (q2 >> 2) * 64; }
        else if (id < 384) { int q2 = id - 320; src = Wv; dst = WkvT + 256 * 1024; Ncols = 256; n0 = (q2 & 3) * 64; k0 = (q2 >> 2) * 64; }
        else if (id < 640) { int q2 = id - 384; src = Wo; dst = WoT; Ncols = 1024; n0 = (q2 & 15) * 64; k0 = (q2 >> 4) * 64; }
        else if (id < 720) {
            int idx = (id - 640) * 256 + tid;
            int row = idx >> 6, col = idx & 63;
            float val = 0.f;
            if (row < 255) val = emb_t[row * 64 + col];
            else if (row >= 256 && row < 271) val = emb_f[(row - 256) * 64 + col];
            embc[idx] = (half_t)val;
            return;
        } else return;
        #pragma unroll
        for (int i2 = 0; i2 < 4; i2++) {
            int idx = i2 * 256 + tid;
            int r = idx >> 4, c4 = (idx & 15) * 4;
            *(float4*)&t[r][c4] = *(const float4*)&src[(size_t)(k0 + r) * Ncols + n0 + c4];
        }
        __syncthreads();
        #pragma unroll
        for (int i2 = 0; i2 < 2; i2++) {
            int idx = i2 * 256 + tid;
            int n = idx >> 3, kb = (idx & 7) * 8;
            half8 o;
            #pragma unroll
            for (int u = 0; u < 8; u++) o[u] = (half_t)t[kb + u][n];
            *(half8*)&dst[(size_t)(n0 + n) * 1024 + k0 + kb] = o;
        }
    }
}

// ---------------------------------------------------------------------------
// proj (512 thr, 8 waves, K-split): two 4-wave groups each GEMM half of K
// (BK=64 x 8 iters, double-buffered, register prefetch), fp32 LDS merge.
// phase 0: blocks 0..255 q-proj (fp16, x0.125*log2e), 256..383 k/v-proj
// (LDS-transpose epilogue). phase 1: out-proj (fp32 out).
// ---------------------------------------------------------------------------
__global__ __launch_bounds__(512) void proj(int phase,
                                            const float* __restrict__ qin,
                                            const float* __restrict__ kin,
                                            const float* __restrict__ vin,
                                            const half_t* __restrict__ AO,
                                            const half_t* __restrict__ WqT,
                                            const half_t* __restrict__ WkvT,
                                            const half_t* __restrict__ WoT,
                                            half_t* __restrict__ qs_h,
                                            half_t* __restrict__ kp_h,
                                            half_t* __restrict__ vpT,
                                            float* __restrict__ out,
                                            float* __restrict__ out_k,
                                            float* __restrict__ out_v)
{
    __shared__ __align__(16) half_t As[2][2][64 * 72];
    __shared__ __align__(16) half_t Bs[2][2][64 * 72];
    const int id = blockIdx.x;
    int task, m0, n0;
    const float* Af = nullptr; const half_t* Ah = nullptr; const half_t* Bt;
    if (phase == 1)      { task = 2; m0 = (id >> 4) * 64; n0 = (id & 15) * 64; Ah = AO; Bt = WoT; }
    else if (id < 256)   { task = 0; m0 = (id >> 4) * 64; n0 = (id & 15) * 64; Af = qin; Bt = WqT; }
    else { task = 1; int t = id - 256; m0 = (t >> 3) * 64; n0 = (t & 7) * 64;
           Af = (n0 < 256) ? kin : vin; Bt = WkvT; }

    const int tid = threadIdx.x;
    const int kh = tid >> 8, t8 = tid & 255;
    const int w4 = (tid >> 6) & 3, l = tid & 63;
    const int quad = l >> 4, lr = l & 15, wm = w4 >> 1, wn = w4 & 1;
    const int arow = t8 >> 2, acol = (t8 & 3) * 16;
    const int kbase = kh * 512;

    {   // stage tile 0
        int kk = kbase;
        if (Af) {
            float4 f0 = *(const float4*)&Af[(size_t)(m0 + arow) * 1024 + kk + acol];
            float4 f1 = *(const float4*)&Af[(size_t)(m0 + arow) * 1024 + kk + acol + 4];
            float4 f2 = *(const float4*)&Af[(size_t)(m0 + arow) * 1024 + kk + acol + 8];
            float4 f3 = *(const float4*)&Af[(size_t)(m0 + arow) * 1024 + kk + acol + 12];
            half8 h0, h1;
            h0[0]=(half_t)f0.x; h0[1]=(half_t)f0.y; h0[2]=(half_t)f0.z; h0[3]=(half_t)f0.w;
            h0[4]=(half_t)f1.x; h0[5]=(half_t)f1.y; h0[6]=(half_t)f1.z; h0[7]=(half_t)f1.w;
            h1[0]=(half_t)f2.x; h1[1]=(half_t)f2.y; h1[2]=(half_t)f2.z; h1[3]=(half_t)f2.w;
            h1[4]=(half_t)f3.x; h1[5]=(half_t)f3.y; h1[6]=(half_t)f3.z; h1[7]=(half_t)f3.w;
            *(half8*)&As[kh][0][arow * 72 + acol] = h0;
            *(half8*)&As[kh][0][arow * 72 + acol + 8] = h1;
        } else {
            *(half8*)&As[kh][0][arow * 72 + acol]     = *(const half8*)&Ah[(size_t)(m0 + arow) * 1024 + kk + acol];
            *(half8*)&As[kh][0][arow * 72 + acol + 8] = *(const half8*)&Ah[(size_t)(m0 + arow) * 1024 + kk + acol + 8];
        }
        *(half8*)&Bs[kh][0][arow * 72 + acol]     = *(const half8*)&Bt[(size_t)(n0 + arow) * 1024 + kk + acol];
        *(half8*)&Bs[kh][0][arow * 72 + acol + 8] = *(const half8*)&Bt[(size_t)(n0 + arow) * 1024 + kk + acol + 8];
    }
    __syncthreads();

    floatx4 zero = {0.f, 0.f, 0.f, 0.f};
    floatx4 acc[2][2];
    acc[0][0] = zero; acc[0][1] = zero; acc[1][0] = zero; acc[1][1] = zero;

    float4 pf0, pf1, pf2, pf3; half8 ph0, ph1, pb0, pb1;
    for (int it = 0; it < 8; ++it) {
        if (it < 7) {
            int kk = kbase + (it + 1) * 64;
            if (Af) {
                pf0 = *(const float4*)&Af[(size_t)(m0 + arow) * 1024 + kk + acol];
                pf1 = *(const float4*)&Af[(size_t)(m0 + arow) * 1024 + kk + acol + 4];
                pf2 = *(const float4*)&Af[(size_t)(m0 + arow) * 1024 + kk + acol + 8];
                pf3 = *(const float4*)&Af[(size_t)(m0 + arow) * 1024 + kk + acol + 12];
            } else {
                ph0 = *(const half8*)&Ah[(size_t)(m0 + arow) * 1024 + kk + acol];
                ph1 = *(const half8*)&Ah[(size_t)(m0 + arow) * 1024 + kk + acol + 8];
            }
            pb0 = *(const half8*)&Bt[(size_t)(n0 + arow) * 1024 + kk + acol];
            pb1 = *(const half8*)&Bt[(size_t)(n0 + arow) * 1024 + kk + acol + 8];
        }
        const half_t* Ab = &As[kh][it & 1][0];
        const half_t* Bb = &Bs[kh][it & 1][0];
        #pragma unroll
        for (int ks = 0; ks < 2; ++ks) {
            half8 a0 = *(const half8*)&Ab[(wm * 32 + lr) * 72 + ks * 32 + quad * 8];
            half8 a1 = *(const half8*)&Ab[(wm * 32 + 16 + lr) * 72 + ks * 32 + quad * 8];
            half8 b0 = *(const half8*)&Bb[(wn * 32 + lr) * 72 + ks * 32 + quad * 8];
            half8 b1 = *(const half8*)&Bb[(wn * 32 + 16 + lr) * 72 + ks * 32 + quad * 8];
            acc[0][0] = mfma16(a0, b0, acc[0][0]);
            acc[0][1] = mfma16(a0, b1, acc[0][1]);
            acc[1][0] = mfma16(a1, b0, acc[1][0]);
            acc[1][1] = mfma16(a1, b1, acc[1][1]);
        }
        __syncthreads();
        if (it < 7) {
            int buf = (it + 1) & 1;
            if (Af) {
                half8 h0, h1;
                h0[0]=(half_t)pf0.x; h0[1]=(half_t)pf0.y; h0[2]=(half_t)pf0.z; h0[3]=(half_t)pf0.w;
                h0[4]=(half_t)pf1.x; h0[5]=(half_t)pf1.y; h0[6]=(half_t)pf1.z; h0[7]=(half_t)pf1.w;
                h1[0]=(half_t)pf2.x; h1[1]=(half_t)pf2.y; h1[2]=(half_t)pf2.z; h1[3]=(half_t)pf2.w;
                h1[4]=(half_t)pf3.x; h1[5]=(half_t)pf3.y; h1[6]=(half_t)pf3.z; h1[7]=(half_t)pf3.w;
                *(half8*)&As[kh][buf][arow * 72 + acol] = h0;
                *(half8*)&As[kh][buf][arow * 72 + acol + 8] = h1;
            } else {
                *(half8*)&As[kh][buf][arow * 72 + acol] = ph0;
                *(half8*)&As[kh][buf][arow * 72 + acol + 8] = ph1;
            }
            *(half8*)&Bs[kh][buf][arow * 72 + acol] = pb0;
            *(half8*)&Bs[kh][buf][arow * 72 + acol + 8] = pb1;
            __syncthreads();
        }
    }

    // merge K-halves (kh1 -> LDS fp32, kh0 adds)
    float* M = (float*)&Bs[0][0][0];   // 64 x 66 floats
    if (kh == 1) {
        #pragma unroll
        for (int mi = 0; mi < 2; mi++)
            #pragma unroll
            for (int ni = 0; ni < 2; ni++)
                #pragma unroll
                for (int r = 0; r < 4; r++)
                    M[(wm * 32 + mi * 16 + quad * 4 + r) * 66 + wn * 32 + ni * 16 + lr] = acc[mi][ni][r];
    }
    __syncthreads();
    if (kh == 0) {
        #pragma unroll
        for (int mi = 0; mi < 2; mi++)
            #pragma unroll
            for (int ni = 0; ni < 2; ni++)
                #pragma unroll
                for (int r = 0; r < 4; r++)
                    acc[mi][ni][r] += M[(wm * 32 + mi * 16 + quad * 4 + r) * 66 + wn * 32 + ni * 16 + lr];
    }

    if (task == 0) {
        if (kh == 0) {
            #pragma unroll
            for (int mi = 0; mi < 2; mi++)
                #pragma unroll
                for (int ni = 0; ni < 2; ni++)
                    #pragma unroll
                    for (int r = 0; r < 4; r++) {
                        int m = m0 + wm * 32 + mi * 16 + quad * 4 + r;
                        int n = n0 + wn * 32 + ni * 16 + lr;
                        qs_h[(size_t)m * 1024 + n] = (half_t)(acc[mi][ni][r] * (0.125f * LOG2E));
                    }
        }
    } else if (task == 2) {
        if (kh == 0) {
            #pragma unroll
            for (int mi = 0; mi < 2; mi++)
                #pragma unroll
                for (int ni = 0; ni < 2; ni++)
                    #pragma unroll
                    for (int r = 0; r < 4; r++) {
                        int m = m0 + wm * 32 + mi * 16 + quad * 4 + r;
                        int n = n0 + wn * 32 + ni * 16 + lr;
                        out[(size_t)m * 1024 + n] = acc[mi][ni][r];
                    }
        }
    } else {
        float* Ct = (float*)&As[0][0][0];   // 64 x 68 floats (transposed acc)
        if (kh == 0) {
            #pragma unroll
            for (int mi = 0; mi < 2; mi++)
                #pragma unroll
                for (int ni = 0; ni < 2; ni++)
                    #pragma unroll
                    for (int r = 0; r < 4; r++)
                        Ct[(wn * 32 + ni * 16 + lr) * 68 + wm * 32 + mi * 16 + quad * 4 + r] = acc[mi][ni][r];
        }
        __syncthreads();
        if (kh == 0) {
            const int b = m0 >> 9, jm0 = m0 & 511;
            if (n0 < 256) {
                int gg = n0 >> 6;
                {
                    int d = t8 >> 2, jc = (t8 & 3) * 16;
                    float4 vv[4];
                    #pragma unroll
                    for (int u = 0; u < 4; u++) vv[u] = *(float4*)&Ct[d * 68 + jc + u * 4];
                    #pragma unroll
                    for (int t = 0; t < 4; t++)
                        #pragma unroll
                        for (int u = 0; u < 4; u++)
                            *(float4*)&out_k[((size_t)((b * 16 + gg * 4 + t) * 64 + d)) * 1536 + 1024 + jm0 + jc + u * 4] = vv[u];
                }
                {
                    int j = t8 >> 2, dc = (t8 & 3) * 16;
                    half8 o0, o1;
                    #pragma unroll
                    for (int u = 0; u < 8; u++) o0[u] = (half_t)Ct[(dc + u) * 68 + j];
                    #pragma unroll
                    for (int u = 0; u < 8; u++) o1[u] = (half_t)Ct[(dc + 8 + u) * 68 + j];
                    *(half8*)&kp_h[((size_t)(b * 512 + jm0 + j)) * 256 + n0 + dc] = o0;
                    *(half8*)&kp_h[((size_t)(b * 512 + jm0 + j)) * 256 + n0 + dc + 8] = o1;
                }
            } else {
                int gg = (n0 - 256) >> 6;
                {
                    int j = t8 >> 2, dc = (t8 & 3) * 16;
                    float4 vv[4];
                    #pragma unroll
                    for (int u = 0; u < 4; u++) {
                        float4 x;
                        x.x = Ct[(dc + u * 4 + 0) * 68 + j];
                        x.y = Ct[(dc + u * 4 + 1) * 68 + j];
                        x.z = Ct[(dc + u * 4 + 2) * 68 + j];
                        x.w = Ct[(dc + u * 4 + 3) * 68 + j];
                        vv[u] = x;
                    }
                    #pragma unroll
                    for (int t = 0; t < 4; t++)
                        #pragma unroll
                        for (int u = 0; u < 4; u++)
                            *(float4*)&out_v[(((size_t)(b * 16 + gg * 4 + t) * 1536) + 1024 + jm0 + j) * 64 + dc + u * 4] = vv[u];
                }
                {
                    int d = t8 >> 2, jc = (t8 & 3) * 16;
                    half8 o0, o1;
                    #pragma unroll
                    for (int u = 0; u < 8; u++) o0[u] = (half_t)Ct[d * 68 + jc + u];
                    #pragma unroll
                    for (int u = 0; u < 8; u++) o1[u] = (half_t)Ct[d * 68 + jc + 8 + u];
                    *(half8*)&vpT[((size_t)((b * 4 + gg) * 64 + d)) * 512 + jm0 + jc] = o0;
                    *(half8*)&vpT[((size_t)((b * 4 + gg) * 64 + d)) * 512 + jm0 + jc + 8] = o1;
                }
            }
        }
    }
}

// ---------------------------------------------------------------------------
// Flash attention v3: 512 thr / 8 waves. Wave (wq, jh): Q-rows [wq*16,+16),
// j-half jh of each 128-j tile; private online softmax merged at end via LDS.
// exp2-domain (ln2 folded into qs scale). Grid (bh=32, itile=8) XCD-swizzled.
// ---------------------------------------------------------------------------
__global__ __launch_bounds__(512) void flash(const half_t* __restrict__ qs_h,
                                             const half_t* __restrict__ Kc,
                                             const half_t* __restrict__ kp_h,
                                             const half_t* __restrict__ VcT,
                                             const half_t* __restrict__ vpT,
                                             const half_t* __restrict__ embc,
                                             half_t* __restrict__ AO)
{
    __shared__ __align__(16) half_t Qs[64 * 72];     //  9216 B
    __shared__ __align__(16) half_t Ks[128 * 72];    // 18432 B
    __shared__ __align__(16) half_t Vs[64 * 136];    // 17408 B
    __shared__ __align__(16) half_t Ps[64 * 136];    // 17408 B
    __shared__ half_t bt[64 * 210];                  // 26880 B   (t-64 in [0,190], f at 192+)
    const int bh = blockIdx.x, b = bh >> 4, h = bh & 15, g = h >> 2;
    const int i0 = blockIdx.y * 64;
    const int tid = threadIdx.x, w = tid >> 6, l = tid & 63;
    const int quad = l >> 4, lr = l & 15;
    const int wq = w >> 1, jh = w & 1;

    // stage Q (one half8 per thread)
    *(half8*)&Qs[(tid >> 3) * 72 + (tid & 7) * 8] =
        *(const half8*)&qs_h[((size_t)(b * 512 + i0 + (tid >> 3))) * 1024 + h * 64 + (tid & 7) * 8];

    // preload tile-0 K/V into registers
    const int krow = tid >> 2, kc = (tid & 3) * 16;
    const int vd = tid >> 3, vc = (tid & 7) * 16;
    half8 kr0, kr1, vr0, vr1;
    {
        const half_t* ksrc = &Kc[((size_t)bh * 1536 + krow) * 64 + kc];
        const half_t* vsrc = &VcT[((size_t)bh * 64 + vd) * 1536 + vc];
        kr0 = *(const half8*)ksrc; kr1 = *(const half8*)(ksrc + 8);
        vr0 = *(const half8*)vsrc; vr1 = *(const half8*)(vsrc + 8);
    }
    __syncthreads();   // Qs ready

    half8 af0 = *(const half8*)&Qs[(wq * 16 + lr) * 72 + quad * 8];
    half8 af1 = *(const half8*)&Qs[(wq * 16 + lr) * 72 + 32 + quad * 8];

    floatx4 zero = {0.f, 0.f, 0.f, 0.f};
    // bias GEMM for this row-group's bt rows (nf split across the wave pair)
    for (int nf = 4 + jh * 6; nf < (jh ? 17 : 10); ++nf) {
        floatx4 acc = zero;
        half8 b0 = *(const half8*)&embc[(size_t)(nf * 16 + lr) * 64 + quad * 8];
        half8 b1 = *(const half8*)&embc[(size_t)(nf * 16 + lr) * 64 + 32 + quad * 8];
        acc = mfma16(af0, b0, acc);
        acc = mfma16(af1, b1, acc);
        #pragma unroll
        for (int r = 0; r < 4; r++)
            bt[(wq * 16 + quad * 4 + r) * 210 + nf * 16 + lr - 64] = (half_t)acc[r];
    }

    // write tile-0 K/V to LDS
    *(half8*)&Ks[krow * 72 + kc] = kr0;
    *(half8*)&Ks[krow * 72 + kc + 8] = kr1;
    *(half8*)&Vs[vd * 136 + vc] = vr0;
    *(half8*)&Vs[vd * 136 + vc + 8] = vr1;
    __syncthreads();   // bt + tile0 ready

    float bfv[4];
    int qtr[4];
    #pragma unroll
    for (int r = 0; r < 4; r++) {
        int f = ((quad & 1) * 4 + r) - (lr & 7) + 7;     // 0..14
        bfv[r] = (float)bt[(wq * 16 + quad * 4 + r) * 210 + 192 + f];
        qtr[r] = (i0 + wq * 16 + quad * 4 + r) >> 3;
    }

    floatx4 accO[4];
    #pragma unroll
    for (int ni = 0; ni < 4; ni++) accO[ni] = zero;
    float mrun[4] = {-1e30f, -1e30f, -1e30f, -1e30f};
    float lrun[4] = {0.f, 0.f, 0.f, 0.f};

    for (int jt = 0; jt < 16; ++jt) {
        if (jt < 15) {   // prefetch next tile into registers
            const int j1 = (jt + 1) * 128;
            const half_t* ksrc = (j1 < 1536)
                ? &Kc[((size_t)bh * 1536 + j1 + krow) * 64 + kc]
                : &kp_h[((size_t)(b * 512 + j1 - 1536 + krow)) * 256 + g * 64 + kc];
            const half_t* vsrc = (j1 < 1536)
                ? &VcT[((size_t)bh * 64 + vd) * 1536 + j1 + vc]
                : &vpT[((size_t)(b * 4 + g) * 64 + vd) * 512 + (j1 - 1536) + vc];
            kr0 = *(const half8*)ksrc; kr1 = *(const half8*)(ksrc + 8);
            vr0 = *(const half8*)vsrc; vr1 = *(const half8*)(vsrc + 8);
        }

        // S = Q . K^T for this wave's 16 rows x 64 j-cols (jh half)
        floatx4 s[4];
        #pragma unroll
        for (int nj = 0; nj < 4; nj++) {
            int row = jh * 64 + nj * 16 + lr;
            half8 b0 = *(const half8*)&Ks[row * 72 + quad * 8];
            half8 b1 = *(const half8*)&Ks[row * 72 + 32 + quad * 8];
            s[nj] = mfma16(af0, b0, zero);
            s[nj] = mfma16(af1, b1, s[nj]);
        }
        // bias add (exp2 domain already)
        const int ktb = jt * 16 + jh * 8 + (lr >> 3);
        #pragma unroll
        for (int nj = 0; nj < 4; nj++)
            #pragma unroll
            for (int r = 0; r < 4; r++) {
                int toff = 255 + qtr[r] - (ktb + nj * 2);
                toff = min(toff, 190);
                s[nj][r] += (float)bt[(wq * 16 + quad * 4 + r) * 210 + toff] + bfv[r];
            }
        // online softmax (base-2)
        float alpha[4];
        #pragma unroll
        for (int r = 0; r < 4; r++) {
            float tm = fmaxf(fmaxf(s[0][r], s[1][r]), fmaxf(s[2][r], s[3][r]));
            tm = fmaxf(tm, __shfl_xor(tm, 1));
            tm = fmaxf(tm, __shfl_xor(tm, 2));
            tm = fmaxf(tm, __shfl_xor(tm, 4));
            tm = fmaxf(tm, __shfl_xor(tm, 8));
            float mn = fmaxf(mrun[r], tm);
            alpha[r] = exp2f(mrun[r] - mn);
            mrun[r] = mn;
        }
        float psum[4] = {0.f, 0.f, 0.f, 0.f};
        #pragma unroll
        for (int nj = 0; nj < 4; nj++)
            #pragma unroll
            for (int r = 0; r < 4; r++) {
                float p = exp2f(s[nj][r] - mrun[r]);
                s[nj][r] = p;
                psum[r] += p;
            }
        #pragma unroll
        for (int r = 0; r < 4; r++) {
            float ps = psum[r];
            ps += __shfl_xor(ps, 1);
            ps += __shfl_xor(ps, 2);
            ps += __shfl_xor(ps, 4);
            ps += __shfl_xor(ps, 8);
            lrun[r] = lrun[r] * alpha[r] + ps;
        }
        #pragma unroll
        for (int ni = 0; ni < 4; ni++)
            #pragma unroll
            for (int r = 0; r < 4; r++) accO[ni][r] *= alpha[r];
        // P -> LDS (wave-private slice: rows wq*16.., cols jh*64..)
        #pragma unroll
        for (int nj = 0; nj < 4; nj++)
            #pragma unroll
            for (int r = 0; r < 4; r++)
                Ps[(wq * 16 + quad * 4 + r) * 136 + jh * 64 + nj * 16 + lr] = (half_t)s[nj][r];
        // PV accumulate over this wave's 64-j half
        #pragma unroll
        for (int ks = 0; ks < 2; ks++) {
            half8 pa = *(const half8*)&Ps[(wq * 16 + lr) * 136 + jh * 64 + ks * 32 + quad * 8];
            #pragma unroll
            for (int ni = 0; ni < 4; ni++) {
                half8 vb = *(const half8*)&Vs[(ni * 16 + lr) * 136 + jh * 64 + ks * 32 + quad * 8];
                accO[ni] = mfma16(pa, vb, accO[ni]);
            }
        }
        __syncthreads();   // all waves done with Ks/Vs
        if (jt < 15) {
            *(half8*)&Ks[krow * 72 + kc] = kr0;
            *(half8*)&Ks[krow * 72 + kc + 8] = kr1;
            *(half8*)&Vs[vd * 136 + vc] = vr0;
            *(half8*)&Vs[vd * 136 + vc + 8] = vr1;
            __syncthreads();
        }
    }

    // merge jh halves: jh1 publishes (m,l,O), jh0 combines and writes AO
    float* MB = (float*)Ks;   // 64 x 66 floats = 16896 B
    float* ML = (float*)Vs;   // 128 floats
    if (jh == 1) {
        #pragma unroll
        for (int r = 0; r < 4; r++) {
            int row = wq * 16 + quad * 4 + r;
            ML[row] = mrun[r];
            ML[64 + row] = lrun[r];
        }
        #pragma unroll
        for (int ni = 0; ni < 4; ni++)
            #pragma unroll
            for (int r = 0; r < 4; r++)
                MB[(wq * 16 + quad * 4 + r) * 66 + ni * 16 + lr] = accO[ni][r];
    }
    __syncthreads();
    if (jh == 0) {
        float sc0[4], sc1[4];
        #pragma unroll
        for (int r = 0; r < 4; r++) {
            int row = wq * 16 + quad * 4 + r;
            float m1 = ML[row], l1 = ML[64 + row];
            float m = fmaxf(mrun[r], m1);
            float a0 = exp2f(mrun[r] - m), a1 = exp2f(m1 - m);
            float inv = 1.0f / (lrun[r] * a0 + l1 * a1);
            sc0[r] = a0 * inv; sc1[r] = a1 * inv;
        }
        #pragma unroll
        for (int ni = 0; ni < 4; ni++)
            #pragma unroll
            for (int r = 0; r < 4; r++) {
                int row = wq * 16 + quad * 4 + r;
                float o = accO[ni][r] * sc0[r] + MB[row * 66 + ni * 16 + lr] * sc1[r];
                AO[((size_t)(b * 512 + i0 + row)) * 1024 + h * 64 + ni * 16 + lr] = (half_t)o;
            }
    }
}

// ---------------------------------------------------------------------------
extern "C" void kernel_launch(void* const* d_in, const int* in_sizes, int n_in,
                              void* d_out, int out_size, void* d_ws, size_t ws_size,
                              hipStream_t stream)
{
    const float* q       = (const float*)d_in[0];
    const float* k       = (const float*)d_in[1];
    const float* v       = (const float*)d_in[2];
    const float* cache_k = (const float*)d_in[3];
    const float* cache_v = (const float*)d_in[4];
    const float* Wq      = (const float*)d_in[5];
    const float* Wk      = (const float*)d_in[6];
    const float* Wv      = (const float*)d_in[7];
    const float* Wo      = (const float*)d_in[8];
    const float* emb_t   = (const float*)d_in[9];
    const float* emb_f   = (const float*)d_in[10];

    float* out   = (float*)d_out;                 // (2,512,1024)
    float* out_k = out + 1048576;                 // (32,64,1536)
    float* out_v = out_k + 3145728;               // (32,1536,64)

    half_t* ws = (half_t*)d_ws;
    half_t* qs_h = ws;                  // 1048576
    half_t* kp_h = ws + 1048576;        //  262144
    half_t* vpT  = ws + 1310720;        //  262144
    half_t* Kc   = ws + 1572864;        // 3145728
    half_t* VcT  = ws + 4718592;        // 3145728
    half_t* WqT  = ws + 7864320;        // 1048576
    half_t* WkvT = ws + 8912896;        //  524288
    half_t* WoT  = ws + 9437184;        // 1048576
    half_t* embc = ws + 10485760;       //   20480
    half_t* AO   = ws + 10506240;       // 1048576

    prep<<<dim3(24, 32, 3), 256, 0, stream>>>(cache_k, cache_v, Wq, Wk, Wv, Wo,
                                              emb_t, emb_f, Kc, VcT, out_k, out_v,
                                              WqT, WkvT, WoT, embc);
    proj<<<dim3(384), 512, 0, stream>>>(0, q, k, v, nullptr, WqT, WkvT, WoT,
                                        qs_h, kp_h, vpT, out, out_k, out_v);
    flash<<<dim3(32, 8), 512, 0, stream>>>(qs_h, Kc, kp_h, VcT, vpT, embc, AO);
    proj<<<dim3(256), 512, 0, stream>>>(1, q, k, v, AO, WqT, WkvT, WoT,
                                        qs_h, kp_h, vpT, out, out_k, out_v);
}

// Round 6
// 173.747 us; speedup vs baseline: 7.3628x; 1.0443x over previous
//
#include <hip/hip_runtime.h>
#include <math.h>

typedef _Float16 half_t;
typedef _Float16 half8  __attribute__((ext_vector_type(8)));
typedef _Float16 half4v __attribute__((ext_vector_type(4)));
typedef float    floatx4 __attribute__((ext_vector_type(4)));

#define LOG2E 1.44269504088896f

static __device__ __forceinline__ floatx4 mfma16(half8 a, half8 b, floatx4 c) {
    return __builtin_amdgcn_mfma_f32_16x16x32_f16(a, b, c, 0, 0, 0);
}
static __device__ __forceinline__ floatx4 mfma16x16(half4v a, half4v b, floatx4 c) {
    return __builtin_amdgcn_mfma_f32_16x16x16f16(a, b, c, 0, 0, 0);
}

// ---------------------------------------------------------------------------
// prep (256 thr): z=0 cache_k -> Kc[bh][j][d] fp16 + out_k shift fp32
//                 z=1 cache_v -> VcT[bh][d][j] fp16 + out_v shift fp32
//                 z=2 weight transposes + embc build. All float4 loads.
// ---------------------------------------------------------------------------
__global__ __launch_bounds__(256) void prep(const float* __restrict__ cache_k,
                                            const float* __restrict__ cache_v,
                                            const float* __restrict__ Wq,
                                            const float* __restrict__ Wk,
                                            const float* __restrict__ Wv,
                                            const float* __restrict__ Wo,
                                            const float* __restrict__ emb_t,
                                            const float* __restrict__ emb_f,
                                            half_t* __restrict__ Kc,
                                            half_t* __restrict__ VcT,
                                            float* __restrict__ out_k,
                                            float* __restrict__ out_v,
                                            half_t* __restrict__ WqT,
                                            half_t* __restrict__ WkvT,
                                            half_t* __restrict__ WoT,
                                            half_t* __restrict__ embc)
{
    const int tid = threadIdx.x;
    const int z = blockIdx.z;
    __shared__ float t[64][65];
    if (z == 0) {
        const int bh = blockIdx.y, j0 = blockIdx.x * 64;
        const bool shift = (j0 >= 512);
        #pragma unroll
        for (int i2 = 0; i2 < 4; i2++) {
            int idx = i2 * 256 + tid;
            int d = idx >> 4, j4 = (idx & 15) * 4;
            float4 vv = *(const float4*)&cache_k[((size_t)bh * 64 + d) * 1536 + j0 + j4];
            *(float4*)&t[d][j4] = vv;
            if (shift) *(float4*)&out_k[((size_t)bh * 64 + d) * 1536 + j0 - 512 + j4] = vv;
        }
        __syncthreads();
        #pragma unroll
        for (int i2 = 0; i2 < 2; i2++) {
            int idx = i2 * 256 + tid;
            int j = idx >> 3, db = (idx & 7) * 8;
            half8 o;
            #pragma unroll
            for (int u = 0; u < 8; u++) o[u] = (half_t)t[db + u][j];
            *(half8*)&Kc[((size_t)bh * 1536 + j0 + j) * 64 + db] = o;
        }
    } else if (z == 1) {
        const int bh = blockIdx.y, j0 = blockIdx.x * 64;
        const bool shift = (j0 >= 512);
        #pragma unroll
        for (int i2 = 0; i2 < 4; i2++) {
            int idx = i2 * 256 + tid;
            int j = idx >> 4, d4 = (idx & 15) * 4;
            float4 vv = *(const float4*)&cache_v[((size_t)bh * 1536 + j0 + j) * 64 + d4];
            *(float4*)&t[j][d4] = vv;
            if (shift) *(float4*)&out_v[((size_t)bh * 1536 + j0 + j - 512) * 64 + d4] = vv;
        }
        __syncthreads();
        #pragma unroll
        for (int i2 = 0; i2 < 2; i2++) {
            int idx = i2 * 256 + tid;
            int d = idx >> 3, jb = (idx & 7) * 8;
            half8 o;
            #pragma unroll
            for (int u = 0; u < 8; u++) o[u] = (half_t)t[jb + u][d];
            *(half8*)&VcT[((size_t)bh * 64 + d) * 1536 + j0 + jb] = o;
        }
    } else {
        const int id = blockIdx.y * 24 + blockIdx.x;
        const float* src; half_t* dst; int Ncols, n0, k0;
        if (id < 256)      { src = Wq; dst = WqT; Ncols = 1024; n0 = (id & 15) * 64; k0 = (id >> 4) * 64; }
        else if (id < 320) { int q2 = id - 256; src = Wk; dst = WkvT; Ncols = 256; n0 = (q2 & 3) * 64; k0 = (q2 >> 2) * 64; }
        else if (id < 384) { int q2 = id - 320; src = Wv; dst = WkvT + 256 * 1024; Ncols = 256; n0 = (q2 & 3) * 64; k0 = (q2 >> 2) * 64; }
        else if (id < 640) { int q2 = id - 384; src = Wo; dst = WoT; Ncols = 1024; n0 = (q2 & 15) * 64; k0 = (q2 >> 4) * 64; }
        else if (id < 720) {
            int idx = (id - 640) * 256 + tid;
            int row = idx >> 6, col = idx & 63;
            float val = 0.f;
            if (row < 255) val = emb_t[row * 64 + col];
            else if (row >= 256 && row < 271) val = emb_f[(row - 256) * 64 + col];
            embc[idx] = (half_t)val;
            return;
        } else return;
        #pragma unroll
        for (int i2 = 0; i2 < 4; i2++) {
            int idx = i2 * 256 + tid;
            int r = idx >> 4, c4 = (idx & 15) * 4;
            *(float4*)&t[r][c4] = *(const float4*)&src[(size_t)(k0 + r) * Ncols + n0 + c4];
        }
        __syncthreads();
        #pragma unroll
        for (int i2 = 0; i2 < 2; i2++) {
            int idx = i2 * 256 + tid;
            int n = idx >> 3, kb = (idx & 7) * 8;
            half8 o;
            #pragma unroll
            for (int u = 0; u < 8; u++) o[u] = (half_t)t[kb + u][n];
            *(half8*)&dst[(size_t)(n0 + n) * 1024 + k0 + kb] = o;
        }
    }
}

// ---------------------------------------------------------------------------
// proj (512 thr, 8 waves, K-split): two 4-wave groups each GEMM half of K
// (BK=64 x 8 iters, double-buffered, register prefetch), fp32 LDS merge.
// phase 0: blocks 0..255 q-proj (fp16, x0.125*log2e), 256..383 k/v-proj
// (LDS-transpose epilogue). phase 1: out-proj (fp32 out).
// ---------------------------------------------------------------------------
__global__ __launch_bounds__(512) void proj(int phase,
                                            const float* __restrict__ qin,
                                            const float* __restrict__ kin,
                                            const float* __restrict__ vin,
                                            const half_t* __restrict__ AO,
                                            const half_t* __restrict__ WqT,
                                            const half_t* __restrict__ WkvT,
                                            const half_t* __restrict__ WoT,
                                            half_t* __restrict__ qs_h,
                                            half_t* __restrict__ kp_h,
                                            half_t* __restrict__ vpT,
                                            float* __restrict__ out,
                                            float* __restrict__ out_k,
                                            float* __restrict__ out_v)
{
    __shared__ __align__(16) half_t As[2][2][64 * 72];
    __shared__ __align__(16) half_t Bs[2][2][64 * 72];
    const int id = blockIdx.x;
    int task, m0, n0;
    const float* Af = nullptr; const half_t* Ah = nullptr; const half_t* Bt;
    if (phase == 1)      { task = 2; m0 = (id >> 4) * 64; n0 = (id & 15) * 64; Ah = AO; Bt = WoT; }
    else if (id < 256)   { task = 0; m0 = (id >> 4) * 64; n0 = (id & 15) * 64; Af = qin; Bt = WqT; }
    else { task = 1; int t = id - 256; m0 = (t >> 3) * 64; n0 = (t & 7) * 64;
           Af = (n0 < 256) ? kin : vin; Bt = WkvT; }

    const int tid = threadIdx.x;
    const int kh = tid >> 8, t8 = tid & 255;
    const int w4 = (tid >> 6) & 3, l = tid & 63;
    const int quad = l >> 4, lr = l & 15, wm = w4 >> 1, wn = w4 & 1;
    const int arow = t8 >> 2, acol = (t8 & 3) * 16;
    const int kbase = kh * 512;

    {   // stage tile 0
        int kk = kbase;
        if (Af) {
            float4 f0 = *(const float4*)&Af[(size_t)(m0 + arow) * 1024 + kk + acol];
            float4 f1 = *(const float4*)&Af[(size_t)(m0 + arow) * 1024 + kk + acol + 4];
            float4 f2 = *(const float4*)&Af[(size_t)(m0 + arow) * 1024 + kk + acol + 8];
            float4 f3 = *(const float4*)&Af[(size_t)(m0 + arow) * 1024 + kk + acol + 12];
            half8 h0, h1;
            h0[0]=(half_t)f0.x; h0[1]=(half_t)f0.y; h0[2]=(half_t)f0.z; h0[3]=(half_t)f0.w;
            h0[4]=(half_t)f1.x; h0[5]=(half_t)f1.y; h0[6]=(half_t)f1.z; h0[7]=(half_t)f1.w;
            h1[0]=(half_t)f2.x; h1[1]=(half_t)f2.y; h1[2]=(half_t)f2.z; h1[3]=(half_t)f2.w;
            h1[4]=(half_t)f3.x; h1[5]=(half_t)f3.y; h1[6]=(half_t)f3.z; h1[7]=(half_t)f3.w;
            *(half8*)&As[kh][0][arow * 72 + acol] = h0;
            *(half8*)&As[kh][0][arow * 72 + acol + 8] = h1;
        } else {
            *(half8*)&As[kh][0][arow * 72 + acol]     = *(const half8*)&Ah[(size_t)(m0 + arow) * 1024 + kk + acol];
            *(half8*)&As[kh][0][arow * 72 + acol + 8] = *(const half8*)&Ah[(size_t)(m0 + arow) * 1024 + kk + acol + 8];
        }
        *(half8*)&Bs[kh][0][arow * 72 + acol]     = *(const half8*)&Bt[(size_t)(n0 + arow) * 1024 + kk + acol];
        *(half8*)&Bs[kh][0][arow * 72 + acol + 8] = *(const half8*)&Bt[(size_t)(n0 + arow) * 1024 + kk + acol + 8];
    }
    __syncthreads();

    floatx4 zero = {0.f, 0.f, 0.f, 0.f};
    floatx4 acc[2][2];
    acc[0][0] = zero; acc[0][1] = zero; acc[1][0] = zero; acc[1][1] = zero;

    float4 pf0, pf1, pf2, pf3; half8 ph0, ph1, pb0, pb1;
    for (int it = 0; it < 8; ++it) {
        if (it < 7) {
            int kk = kbase + (it + 1) * 64;
            if (Af) {
                pf0 = *(const float4*)&Af[(size_t)(m0 + arow) * 1024 + kk + acol];
                pf1 = *(const float4*)&Af[(size_t)(m0 + arow) * 1024 + kk + acol + 4];
                pf2 = *(const float4*)&Af[(size_t)(m0 + arow) * 1024 + kk + acol + 8];
                pf3 = *(const float4*)&Af[(size_t)(m0 + arow) * 1024 + kk + acol + 12];
            } else {
                ph0 = *(const half8*)&Ah[(size_t)(m0 + arow) * 1024 + kk + acol];
                ph1 = *(const half8*)&Ah[(size_t)(m0 + arow) * 1024 + kk + acol + 8];
            }
            pb0 = *(const half8*)&Bt[(size_t)(n0 + arow) * 1024 + kk + acol];
            pb1 = *(const half8*)&Bt[(size_t)(n0 + arow) * 1024 + kk + acol + 8];
        }
        const half_t* Ab = &As[kh][it & 1][0];
        const half_t* Bb = &Bs[kh][it & 1][0];
        #pragma unroll
        for (int ks = 0; ks < 2; ++ks) {
            half8 a0 = *(const half8*)&Ab[(wm * 32 + lr) * 72 + ks * 32 + quad * 8];
            half8 a1 = *(const half8*)&Ab[(wm * 32 + 16 + lr) * 72 + ks * 32 + quad * 8];
            half8 b0 = *(const half8*)&Bb[(wn * 32 + lr) * 72 + ks * 32 + quad * 8];
            half8 b1 = *(const half8*)&Bb[(wn * 32 + 16 + lr) * 72 + ks * 32 + quad * 8];
            acc[0][0] = mfma16(a0, b0, acc[0][0]);
            acc[0][1] = mfma16(a0, b1, acc[0][1]);
            acc[1][0] = mfma16(a1, b0, acc[1][0]);
            acc[1][1] = mfma16(a1, b1, acc[1][1]);
        }
        __syncthreads();
        if (it < 7) {
            int buf = (it + 1) & 1;
            if (Af) {
                half8 h0, h1;
                h0[0]=(half_t)pf0.x; h0[1]=(half_t)pf0.y; h0[2]=(half_t)pf0.z; h0[3]=(half_t)pf0.w;
                h0[4]=(half_t)pf1.x; h0[5]=(half_t)pf1.y; h0[6]=(half_t)pf1.z; h0[7]=(half_t)pf1.w;
                h1[0]=(half_t)pf2.x; h1[1]=(half_t)pf2.y; h1[2]=(half_t)pf2.z; h1[3]=(half_t)pf2.w;
                h1[4]=(half_t)pf3.x; h1[5]=(half_t)pf3.y; h1[6]=(half_t)pf3.z; h1[7]=(half_t)pf3.w;
                *(half8*)&As[kh][buf][arow * 72 + acol] = h0;
                *(half8*)&As[kh][buf][arow * 72 + acol + 8] = h1;
            } else {
                *(half8*)&As[kh][buf][arow * 72 + acol] = ph0;
                *(half8*)&As[kh][buf][arow * 72 + acol + 8] = ph1;
            }
            *(half8*)&Bs[kh][buf][arow * 72 + acol] = pb0;
            *(half8*)&Bs[kh][buf][arow * 72 + acol + 8] = pb1;
            __syncthreads();
        }
    }

    // merge K-halves (kh1 -> LDS fp32, kh0 adds)
    float* M = (float*)&Bs[0][0][0];   // 64 x 66 floats
    if (kh == 1) {
        #pragma unroll
        for (int mi = 0; mi < 2; mi++)
            #pragma unroll
            for (int ni = 0; ni < 2; ni++)
                #pragma unroll
                for (int r = 0; r < 4; r++)
                    M[(wm * 32 + mi * 16 + quad * 4 + r) * 66 + wn * 32 + ni * 16 + lr] = acc[mi][ni][r];
    }
    __syncthreads();
    if (kh == 0) {
        #pragma unroll
        for (int mi = 0; mi < 2; mi++)
            #pragma unroll
            for (int ni = 0; ni < 2; ni++)
                #pragma unroll
                for (int r = 0; r < 4; r++)
                    acc[mi][ni][r] += M[(wm * 32 + mi * 16 + quad * 4 + r) * 66 + wn * 32 + ni * 16 + lr];
    }

    if (task == 0) {
        if (kh == 0) {
            #pragma unroll
            for (int mi = 0; mi < 2; mi++)
                #pragma unroll
                for (int ni = 0; ni < 2; ni++)
                    #pragma unroll
                    for (int r = 0; r < 4; r++) {
                        int m = m0 + wm * 32 + mi * 16 + quad * 4 + r;
                        int n = n0 + wn * 32 + ni * 16 + lr;
                        qs_h[(size_t)m * 1024 + n] = (half_t)(acc[mi][ni][r] * (0.125f * LOG2E));
                    }
        }
    } else if (task == 2) {
        if (kh == 0) {
            #pragma unroll
            for (int mi = 0; mi < 2; mi++)
                #pragma unroll
                for (int ni = 0; ni < 2; ni++)
                    #pragma unroll
                    for (int r = 0; r < 4; r++) {
                        int m = m0 + wm * 32 + mi * 16 + quad * 4 + r;
                        int n = n0 + wn * 32 + ni * 16 + lr;
                        out[(size_t)m * 1024 + n] = acc[mi][ni][r];
                    }
        }
    } else {
        float* Ct = (float*)&As[0][0][0];   // 64 x 68 floats (transposed acc)
        if (kh == 0) {
            #pragma unroll
            for (int mi = 0; mi < 2; mi++)
                #pragma unroll
                for (int ni = 0; ni < 2; ni++)
                    #pragma unroll
                    for (int r = 0; r < 4; r++)
                        Ct[(wn * 32 + ni * 16 + lr) * 68 + wm * 32 + mi * 16 + quad * 4 + r] = acc[mi][ni][r];
        }
        __syncthreads();
        if (kh == 0) {
            const int b = m0 >> 9, jm0 = m0 & 511;
            if (n0 < 256) {
                int gg = n0 >> 6;
                {
                    int d = t8 >> 2, jc = (t8 & 3) * 16;
                    float4 vv[4];
                    #pragma unroll
                    for (int u = 0; u < 4; u++) vv[u] = *(float4*)&Ct[d * 68 + jc + u * 4];
                    #pragma unroll
                    for (int t = 0; t < 4; t++)
                        #pragma unroll
                        for (int u = 0; u < 4; u++)
                            *(float4*)&out_k[((size_t)((b * 16 + gg * 4 + t) * 64 + d)) * 1536 + 1024 + jm0 + jc + u * 4] = vv[u];
                }
                {
                    int j = t8 >> 2, dc = (t8 & 3) * 16;
                    half8 o0, o1;
                    #pragma unroll
                    for (int u = 0; u < 8; u++) o0[u] = (half_t)Ct[(dc + u) * 68 + j];
                    #pragma unroll
                    for (int u = 0; u < 8; u++) o1[u] = (half_t)Ct[(dc + 8 + u) * 68 + j];
                    *(half8*)&kp_h[((size_t)(b * 512 + jm0 + j)) * 256 + n0 + dc] = o0;
                    *(half8*)&kp_h[((size_t)(b * 512 + jm0 + j)) * 256 + n0 + dc + 8] = o1;
                }
            } else {
                int gg = (n0 - 256) >> 6;
                {
                    int j = t8 >> 2, dc = (t8 & 3) * 16;
                    float4 vv[4];
                    #pragma unroll
                    for (int u = 0; u < 4; u++) {
                        float4 x;
                        x.x = Ct[(dc + u * 4 + 0) * 68 + j];
                        x.y = Ct[(dc + u * 4 + 1) * 68 + j];
                        x.z = Ct[(dc + u * 4 + 2) * 68 + j];
                        x.w = Ct[(dc + u * 4 + 3) * 68 + j];
                        vv[u] = x;
                    }
                    #pragma unroll
                    for (int t = 0; t < 4; t++)
                        #pragma unroll
                        for (int u = 0; u < 4; u++)
                            *(float4*)&out_v[(((size_t)(b * 16 + gg * 4 + t) * 1536) + 1024 + jm0 + j) * 64 + dc + u * 4] = vv[u];
                }
                {
                    int d = t8 >> 2, jc = (t8 & 3) * 16;
                    half8 o0, o1;
                    #pragma unroll
                    for (int u = 0; u < 8; u++) o0[u] = (half_t)Ct[d * 68 + jc + u];
                    #pragma unroll
                    for (int u = 0; u < 8; u++) o1[u] = (half_t)Ct[d * 68 + jc + 8 + u];
                    *(half8*)&vpT[((size_t)((b * 4 + gg) * 64 + d)) * 512 + jm0 + jc] = o0;
                    *(half8*)&vpT[((size_t)((b * 4 + gg) * 64 + d)) * 512 + jm0 + jc + 8] = o1;
                }
            }
        }
    }
}

// ---------------------------------------------------------------------------
// Flash v4: 256 thr / 4 waves, 32 Q-rows per block, grid (bh=32, it=16)=512.
// S^T via swapped MFMA operands -> P stays in registers as 16x16x16 A-frags.
// No-max exp2 softmax (scores bounded); per-lane row sums, zero per-tile
// shuffles. Wave (wq, jh) = (i-group of 16, j-half of 64). 2 blocks/CU.
// ---------------------------------------------------------------------------
__global__ __launch_bounds__(256) void flash(const half_t* __restrict__ qs_h,
                                             const half_t* __restrict__ Kc,
                                             const half_t* __restrict__ kp_h,
                                             const half_t* __restrict__ VcT,
                                             const half_t* __restrict__ vpT,
                                             const half_t* __restrict__ embc,
                                             half_t* __restrict__ AO)
{
    __shared__ __align__(16) half_t Qs[32 * 72];     //  4608 B
    __shared__ __align__(16) half_t Ks[128 * 72];    // 18432 B
    __shared__ __align__(16) half_t Vs[64 * 136];    // 17408 B
    __shared__ half_t bt[32 * 210];                  // 13440 B
    const int bh = blockIdx.x, b = bh >> 4, h = bh & 15, g = h >> 2;
    const int i0 = blockIdx.y * 32;
    const int tid = threadIdx.x, w = tid >> 6, l = tid & 63;
    const int quad = l >> 4, lr = l & 15;
    const int wq = w >> 1, jh = w & 1;

    // stage Q (32 rows x 64): one half8 per thread
    *(half8*)&Qs[(tid >> 3) * 72 + (tid & 7) * 8] =
        *(const half8*)&qs_h[((size_t)(b * 512 + i0 + (tid >> 3))) * 1024 + h * 64 + (tid & 7) * 8];

    // preload tile-0 K/V into registers (K: 128x64, V^T: 64x128)
    const int krow = tid >> 1, kc = (tid & 1) * 32;
    const int vd = tid >> 2, vc = (tid & 3) * 32;
    half8 kr[4], vr[4];
    {
        const half_t* ksrc = &Kc[((size_t)bh * 1536 + krow) * 64 + kc];
        const half_t* vsrc = &VcT[((size_t)bh * 64 + vd) * 1536 + vc];
        #pragma unroll
        for (int u = 0; u < 4; u++) kr[u] = *(const half8*)(ksrc + u * 8);
        #pragma unroll
        for (int u = 0; u < 4; u++) vr[u] = *(const half8*)(vsrc + u * 8);
    }
    __syncthreads();   // Qs ready

    // Q as B-operand frags (lane n = i = wq*16+lr)
    half8 qf0 = *(const half8*)&Qs[(wq * 16 + lr) * 72 + quad * 8];
    half8 qf1 = *(const half8*)&Qs[(wq * 16 + lr) * 72 + 32 + quad * 8];

    floatx4 zero = {0.f, 0.f, 0.f, 0.f};
    // bias GEMM: bt[i][t-64] = q_i . embc[t], t chunks 4..16 split over jh pair
    {
        int tk0 = jh ? 10 : 4, tk1 = jh ? 17 : 10;
        for (int tk = tk0; tk < tk1; ++tk) {
            floatx4 acc = zero;
            half8 e0 = *(const half8*)&embc[(size_t)(tk * 16 + lr) * 64 + quad * 8];
            half8 e1 = *(const half8*)&embc[(size_t)(tk * 16 + lr) * 64 + 32 + quad * 8];
            acc = mfma16(e0, qf0, acc);        // D[m=t][n=i]
            acc = mfma16(e1, qf1, acc);
            #pragma unroll
            for (int r = 0; r < 4; r++)
                bt[(wq * 16 + lr) * 210 + tk * 16 + quad * 4 + r - 64] = (half_t)acc[r];
        }
    }

    // write tile-0 K/V to LDS
    #pragma unroll
    for (int u = 0; u < 4; u++) *(half8*)&Ks[krow * 72 + kc + u * 8] = kr[u];
    #pragma unroll
    for (int u = 0; u < 4; u++) *(half8*)&Vs[vd * 136 + vc + u * 8] = vr[u];
    __syncthreads();   // bt + tile0 ready

    // per-thread constants: this lane owns row i = wq*16 + lr
    const int qtr = (i0 + wq * 16 + lr) >> 3;
    float bfv[4];
    #pragma unroll
    for (int r = 0; r < 4; r++) {
        int f = (lr & 7) - ((quad & 1) * 4 + r) + 7;     // 0..14
        bfv[r] = (float)bt[(wq * 16 + lr) * 210 + 192 + f];
    }

    floatx4 accO[4];
    #pragma unroll
    for (int ni = 0; ni < 4; ni++) accO[ni] = zero;
    float lrun = 0.f;    // per-lane: row i = wq*16+lr, this wave's j-half

    for (int jt = 0; jt < 16; ++jt) {
        if (jt < 15) {   // prefetch next tile into registers
            const int j1 = (jt + 1) * 128;
            const half_t* ksrc = (j1 < 1536)
                ? &Kc[((size_t)bh * 1536 + j1 + krow) * 64 + kc]
                : &kp_h[((size_t)(b * 512 + j1 - 1536 + krow)) * 256 + g * 64 + kc];
            const half_t* vsrc = (j1 < 1536)
                ? &VcT[((size_t)bh * 64 + vd) * 1536 + j1 + vc]
                : &vpT[((size_t)(b * 4 + g) * 64 + vd) * 512 + (j1 - 1536) + vc];
            #pragma unroll
            for (int u = 0; u < 4; u++) kr[u] = *(const half8*)(ksrc + u * 8);
            #pragma unroll
            for (int u = 0; u < 4; u++) vr[u] = *(const half8*)(vsrc + u * 8);
        }

        // S^T = K . Q^T : D[m=j][n=i], 4 chunks of 16 j
        floatx4 s[4];
        #pragma unroll
        for (int c = 0; c < 4; c++) {
            int row = jh * 64 + c * 16 + lr;
            half8 kf0 = *(const half8*)&Ks[row * 72 + quad * 8];
            half8 kf1 = *(const half8*)&Ks[row * 72 + 32 + quad * 8];
            s[c] = mfma16(kf0, qf0, zero);
            s[c] = mfma16(kf1, qf1, s[c]);
        }
        // bias + exp2 (no max: scores bounded), accumulate per-lane row sum
        const int ktb = jt * 16 + jh * 8 + (quad >> 1);
        const half_t* btrow = &bt[(wq * 16 + lr) * 210];
        #pragma unroll
        for (int c = 0; c < 4; c++)
            #pragma unroll
            for (int r = 0; r < 4; r++) {
                int toff = 255 + qtr - (ktb + c * 2);
                toff = min(toff, 190);
                float p = exp2f(s[c][r] + (float)btrow[toff] + bfv[r]);
                s[c][r] = p;
                lrun += p;
            }
        // P regs -> A-frags (16x16x16: m=lane=i, k=quad*4+r=j) ; PV accumulate
        #pragma unroll
        for (int c = 0; c < 4; c++) {
            half4v pf;
            #pragma unroll
            for (int r = 0; r < 4; r++) pf[r] = (half_t)s[c][r];
            #pragma unroll
            for (int ni = 0; ni < 4; ni++) {
                half4v vb = *(const half4v*)&Vs[(ni * 16 + lr) * 136 + jh * 64 + c * 16 + quad * 4];
                accO[ni] = mfma16x16(pf, vb, accO[ni]);
            }
        }
        __syncthreads();   // all waves done with Ks/Vs
        if (jt < 15) {
            #pragma unroll
            for (int u = 0; u < 4; u++) *(half8*)&Ks[krow * 72 + kc + u * 8] = kr[u];
            #pragma unroll
            for (int u = 0; u < 4; u++) *(half8*)&Vs[vd * 136 + vc + u * 8] = vr[u];
            __syncthreads();
        }
    }

    // reduce row sums across quads (same i lives in lanes l, l^16, l^32)
    float tot = lrun;
    tot += __shfl_xor(tot, 16);
    tot += __shfl_xor(tot, 32);

    // jh merge: jh1 publishes accO + sums, jh0 combines, normalizes, writes
    float* MB = (float*)Ks;   // 32 x 68 fp32
    float* ML = (float*)Vs;   // 128 fp32
    if (jh == 1) {
        if (l < 16) ML[wq * 16 + l] = tot;
        #pragma unroll
        for (int ni = 0; ni < 4; ni++)
            #pragma unroll
            for (int r = 0; r < 4; r++)
                MB[(wq * 16 + quad * 4 + r) * 68 + ni * 16 + lr] = accO[ni][r];
    }
    __syncthreads();
    if (jh == 0) {
        float full = tot + ML[wq * 16 + lr];
        if (l < 16) ML[64 + wq * 16 + l] = full;
        float inv[4];
        #pragma unroll
        for (int r = 0; r < 4; r++) inv[r] = 1.0f / ML[64 + wq * 16 + quad * 4 + r];
        #pragma unroll
        for (int ni = 0; ni < 4; ni++)
            #pragma unroll
            for (int r = 0; r < 4; r++) {
                int row = wq * 16 + quad * 4 + r;
                float o = (accO[ni][r] + MB[row * 68 + ni * 16 + lr]) * inv[r];
                AO[((size_t)(b * 512 + i0 + row)) * 1024 + h * 64 + ni * 16 + lr] = (half_t)o;
            }
    }
}

// ---------------------------------------------------------------------------
extern "C" void kernel_launch(void* const* d_in, const int* in_sizes, int n_in,
                              void* d_out, int out_size, void* d_ws, size_t ws_size,
                              hipStream_t stream)
{
    const float* q       = (const float*)d_in[0];
    const float* k       = (const float*)d_in[1];
    const float* v       = (const float*)d_in[2];
    const float* cache_k = (const float*)d_in[3];
    const float* cache_v = (const float*)d_in[4];
    const float* Wq      = (const float*)d_in[5];
    const float* Wk      = (const float*)d_in[6];
    const float* Wv      = (const float*)d_in[7];
    const float* Wo      = (const float*)d_in[8];
    const float* emb_t   = (const float*)d_in[9];
    const float* emb_f   = (const float*)d_in[10];

    float* out   = (float*)d_out;                 // (2,512,1024)
    float* out_k = out + 1048576;                 // (32,64,1536)
    float* out_v = out_k + 3145728;               // (32,1536,64)

    half_t* ws = (half_t*)d_ws;
    half_t* qs_h = ws;                  // 1048576
    half_t* kp_h = ws + 1048576;        //  262144
    half_t* vpT  = ws + 1310720;        //  262144
    half_t* Kc   = ws + 1572864;        // 3145728
    half_t* VcT  = ws + 4718592;        // 3145728
    half_t* WqT  = ws + 7864320;        // 1048576
    half_t* WkvT = ws + 8912896;        //  524288
    half_t* WoT  = ws + 9437184;        // 1048576
    half_t* embc = ws + 10485760;       //   20480
    half_t* AO   = ws + 10506240;       // 1048576

    prep<<<dim3(24, 32, 3), 256, 0, stream>>>(cache_k, cache_v, Wq, Wk, Wv, Wo,
                                              emb_t, emb_f, Kc, VcT, out_k, out_v,
                                              WqT, WkvT, WoT, embc);
    proj<<<dim3(384), 512, 0, stream>>>(0, q, k, v, nullptr, WqT, WkvT, WoT,
                                        qs_h, kp_h, vpT, out, out_k, out_v);
    flash<<<dim3(32, 16), 256, 0, stream>>>(qs_h, Kc, kp_h, VcT, vpT, embc, AO);
    proj<<<dim3(256), 512, 0, stream>>>(1, q, k, v, AO, WqT, WkvT, WoT,
                                        qs_h, kp_h, vpT, out, out_k, out_v);
}